// Round 9
// baseline (14841.034 us; speedup 1.0000x reference)
//
#include <hip/hip_runtime.h>

typedef unsigned short u16;
typedef unsigned int u32;
typedef __bf16 bf16x8 __attribute__((ext_vector_type(8)));
typedef float f32x4 __attribute__((ext_vector_type(4)));

#define D_    768
#define DM_   3072
#define NL_   12
#define NT_   577
#define NP_   576
#define B_    64
#define MREAL (B_*NT_)      /* 36928 */
#define MPAD2 37120         /* 290*128 */
#define NC_   1000
#define IMG_  384

__device__ __forceinline__ float bf2f(u16 v){
  union { unsigned u; float f; } c; c.u = ((unsigned)v) << 16; return c.f;
}
__device__ __forceinline__ u16 f2bf(float f){
  union { float f; unsigned u; } c; c.f = f;
  unsigned r = c.u + 0x7FFFu + ((c.u >> 16) & 1u);
  return (u16)(r >> 16);
}
__device__ __forceinline__ float gelu_f(float x){
  return 0.5f * x * (1.0f + erff(x * 0.70710678118654752f));
}
__device__ __forceinline__ void gload16(const void* g, void* l){
  __builtin_amdgcn_global_load_lds((const __attribute__((address_space(1))) void*)g,
                                   (__attribute__((address_space(3))) void*)l, 16, 0, 0);
}
#define SB_ __builtin_amdgcn_sched_barrier(0)

// ---------------------------------------------------------------------------
// Wave-private barrier-free GEMM: C[M,N] = A[M,K] bf16 x Bt[N,K] bf16.
// Block 256 thr = 4 waves (2Mx2N); each wave computes a 64x64 tile from its
// OWN private LDS slot (dbuf x {A,B} x [64 rows][32 k]) — NO s_barrier at all.
// Per K-tile(32): issue 8 gload16 (t+1 -> alt buf), vmcnt(8) (retires tile t),
// 8 ds_read_b128 frags, lgkmcnt(0)+sched_barrier (rule 18; also fences next
// iter's gloads off the just-read buffer), 16 MFMA under setprio.
// Swizzle: slot' = slot ^ ((row>>1)&3), applied on SOURCE addr and read addr
// (both-sides, rule 21); <=2-way bank aliasing (free, m136).
// EPI: 0=bf16 bias, 1=f32 bias+res, 2=bf16 gelu(bias), 3=f32 gelu(bias)+res,
//      4=f32 bias, 5=f32 gelu(bias) bounded store [Ms,Ns]
// ---------------------------------------------------------------------------
template<int EPI>
__global__ __launch_bounds__(256, 2) void gemmW_k(
    const u16* __restrict__ A, const u16* __restrict__ Bt,
    const float* __restrict__ bias, const float* __restrict__ res,
    void* __restrict__ outv, int K, int ldo, int nbn, int Ms, int Ns)
{
  __shared__ u16 lds[4][2][2][2048];   // [wave][dbuf][A|B][64*32] = 64 KiB
  const int tid = threadIdx.x;
  const int l   = tid & 63;
  const int w   = tid >> 6;
  const int wm  = w >> 1, wn = w & 1;
  const int lrow = l & 15;
  const int g    = l >> 4;

  // bijective XCD swizzle (m204), bn-fastest
  const int nwg = gridDim.x;
  const int q = nwg >> 3, r = nwg & 7;
  const int xcd = blockIdx.x & 7, o = blockIdx.x >> 3;
  const int wg = (xcd < r ? xcd * (q + 1) : r * (q + 1) + (xcd - r) * q) + o;
  const int bm = wg / nbn, bn = wg % nbn;

  const int arow0 = bm*128 + wm*64;
  const int brow0 = bn*128 + wn*64;

  // staging: lane covers row (l>>2)+16j, 16B slot (l&3); source pre-swizzle
  // slot_src = (l&3) ^ ((l>>3)&3)  (j-independent: rows step by 16)
  const int srow = l >> 2;
  const int scol = ((l & 3) ^ ((l >> 3) & 3)) * 8;   // elements
  const u16* aS = A  + (size_t)(arow0 + srow) * K + scol;
  const u16* bS = Bt + (size_t)(brow0 + srow) * K + scol;
  const size_t rstep = (size_t)16 * K;   // 16 rows per gload16

  // fragment read byte offsets within a [64][32] tile (same for A and B)
  int fro[4];
  #pragma unroll
  for (int mi = 0; mi < 4; mi++) {
    const int row = mi*16 + lrow;
    fro[mi] = row*64 + ((g ^ ((lrow >> 1) & 3)) << 4);
  }

  f32x4 acc[4][4];
  #pragma unroll
  for (int i = 0; i < 4; i++)
    #pragma unroll
    for (int j = 0; j < 4; j++) acc[i][j] = {0.f, 0.f, 0.f, 0.f};

  const int nk = K >> 5;   // BK=32

  // prologue: stage tile 0 -> buf 0 (8 loads, stay in flight)
  {
    char* dA = (char*)&lds[w][0][0][0];
    char* dB = (char*)&lds[w][0][1][0];
    #pragma unroll
    for (int j = 0; j < 4; j++) gload16(aS + j*rstep, dA + l*16 + j*1024);
    #pragma unroll
    for (int j = 0; j < 4; j++) gload16(bS + j*rstep, dB + l*16 + j*1024);
  }

  for (int t = 0; t < nk; ++t) {
    const int cur = t & 1;
    if (t + 1 < nk) {
      const int ko = (t + 1) * 32;
      char* dA = (char*)&lds[w][cur^1][0][0];
      char* dB = (char*)&lds[w][cur^1][1][0];
      #pragma unroll
      for (int j = 0; j < 4; j++) gload16(aS + ko + j*rstep, dA + l*16 + j*1024);
      #pragma unroll
      for (int j = 0; j < 4; j++) gload16(bS + ko + j*rstep, dB + l*16 + j*1024);
      asm volatile("s_waitcnt vmcnt(8)" ::: "memory");
    } else {
      asm volatile("s_waitcnt vmcnt(0)" ::: "memory");
    }
    const char* As_ = (const char*)&lds[w][cur][0][0];
    const char* Bs_ = (const char*)&lds[w][cur][1][0];
    bf16x8 af[4], bfr[4];
    #pragma unroll
    for (int mi = 0; mi < 4; mi++) af[mi]  = *(const bf16x8*)(As_ + fro[mi]);
    #pragma unroll
    for (int ni = 0; ni < 4; ni++) bfr[ni] = *(const bf16x8*)(Bs_ + fro[ni]);
    asm volatile("s_waitcnt lgkmcnt(0)" ::: "memory");
    SB_;
    __builtin_amdgcn_s_setprio(1);
    #pragma unroll
    for (int mi = 0; mi < 4; mi++)
      #pragma unroll
      for (int ni = 0; ni < 4; ni++)
        acc[mi][ni] = __builtin_amdgcn_mfma_f32_16x16x32_bf16(af[mi], bfr[ni], acc[mi][ni], 0, 0, 0);
    __builtin_amdgcn_s_setprio(0);
  }

  const int orow0 = arow0;
  const int ocol0 = brow0;
  #pragma unroll
  for (int mi = 0; mi < 4; mi++) {
    #pragma unroll
    for (int ni = 0; ni < 4; ni++) {
      const int col = ocol0 + ni*16 + lrow;
      float bv;
      if constexpr (EPI == 5) bv = (col < Ns) ? bias[col] : 0.f;
      else bv = bias[col];
      #pragma unroll
      for (int r2 = 0; r2 < 4; r2++) {
        const int row = orow0 + mi*16 + g*4 + r2;
        const float v = acc[mi][ni][r2] + bv;
        const size_t idx = (size_t)row * ldo + col;
        if constexpr (EPI == 0) ((u16*)outv)[idx] = f2bf(v);
        else if constexpr (EPI == 1) ((float*)outv)[idx] = v + res[idx];
        else if constexpr (EPI == 2) ((u16*)outv)[idx] = f2bf(gelu_f(v));
        else if constexpr (EPI == 3) ((float*)outv)[idx] = gelu_f(v) + res[idx];
        else if constexpr (EPI == 4) ((float*)outv)[idx] = v;
        else if constexpr (EPI == 5) {
          if (row < Ms && col < Ns) ((float*)outv)[(size_t)row * Ns + col] = gelu_f(v);
        }
      }
    }
  }
}

// ---------------------------------------------------------------------------
__global__ void wconv_k(const float* __restrict__ W, u16* __restrict__ Wt,
                        int K, int N)
{
  __shared__ float tile[32][33];
  const int n0 = blockIdx.x * 32, k0 = blockIdx.y * 32;
  const int tx = threadIdx.x, ty = threadIdx.y;
  #pragma unroll
  for (int r = 0; r < 4; r++) {
    const int kk = k0 + ty + r*8;
    const int nn = n0 + tx;
    tile[ty + r*8][tx] = (nn < N) ? W[(size_t)kk * N + nn] : 0.f;
  }
  __syncthreads();
  #pragma unroll
  for (int r = 0; r < 4; r++) {
    const int nn = n0 + ty + r*8;
    Wt[(size_t)nn * K + k0 + tx] = f2bf(tile[tx][ty + r*8]);
  }
}

// ---------------------------------------------------------------------------
__global__ void patchify_k(const float* __restrict__ x, u16* __restrict__ hb)
{
  const int blk = blockIdx.x;
  const int b = blk / NP_, p = blk % NP_;
  const int pr = p / 24, pc = p % 24;
  const size_t row = (size_t)b * NT_ + 1 + p;
  #pragma unroll
  for (int u = 0; u < 3; u++) {
    const int j  = threadIdx.x + u * 256;
    const int c  = j >> 8, ph = (j >> 4) & 15, pw = j & 15;
    const float v = x[((size_t)(b*3 + c) * IMG_ + pr*16 + ph) * IMG_ + pc*16 + pw];
    hb[row * D_ + j] = f2bf(v);
  }
}

__global__ void posecls_k(float* __restrict__ z, const float* __restrict__ ce,
                          const float* __restrict__ pe)
{
  const int row = blockIdx.x;
  const int t = row % NT_;
  const size_t base = (size_t)row * D_;
  #pragma unroll
  for (int u = 0; u < 3; u++) {
    const int j = threadIdx.x + u * 256;
    if (t == 0) z[base + j] = ce[j] + pe[j];
    else        z[base + j] += pe[(size_t)t * D_ + j];
  }
}

// LayerNorm: one wave per row, float4 loads, f32 in -> bf16 out
__global__ void ln_k(const float* __restrict__ z, const float* __restrict__ w,
                     const float* __restrict__ b, u16* __restrict__ out)
{
  const int row = blockIdx.x * 4 + (threadIdx.x >> 6);
  const int l = threadIdx.x & 63;
  const float4* zr = (const float4*)(z + (size_t)row * D_);
  float4 xq[3];
  float s = 0.f;
  #pragma unroll
  for (int j = 0; j < 3; j++) {
    xq[j] = zr[j*64 + l];
    s += xq[j].x + xq[j].y + xq[j].z + xq[j].w;
  }
  #pragma unroll
  for (int m = 1; m < 64; m <<= 1) s += __shfl_xor(s, m, 64);
  const float mean = s * (1.0f / 768.0f);
  float ss = 0.f;
  #pragma unroll
  for (int j = 0; j < 3; j++) {
    const float dx = xq[j].x-mean, dy = xq[j].y-mean, dz = xq[j].z-mean, dw = xq[j].w-mean;
    ss += dx*dx + dy*dy + dz*dz + dw*dw;
  }
  #pragma unroll
  for (int m = 1; m < 64; m <<= 1) ss += __shfl_xor(ss, m, 64);
  const float rinv = rsqrtf(ss * (1.0f / 768.0f) + 1e-5f);
  const size_t ob = (size_t)row * D_;
  #pragma unroll
  for (int j = 0; j < 3; j++) {
    const int c = (j*64 + l) * 4;
    const float4 wv = *(const float4*)(w + c);
    const float4 bv = *(const float4*)(b + c);
    ushort4 ov;
    ov.x = f2bf((xq[j].x - mean) * rinv * wv.x + bv.x);
    ov.y = f2bf((xq[j].y - mean) * rinv * wv.y + bv.y);
    ov.z = f2bf((xq[j].z - mean) * rinv * wv.z + bv.z);
    ov.w = f2bf((xq[j].w - mean) * rinv * wv.w + bv.w);
    *(ushort4*)(out + ob + c) = ov;
  }
}

// Final LN over cls rows -> yb[128][768] bf16 (rows >= 64 zeroed)
__global__ void lncls_k(const float* __restrict__ z, const float* __restrict__ w,
                        const float* __restrict__ b, u16* __restrict__ out)
{
  const int row = blockIdx.x * 4 + (threadIdx.x >> 6);   // 0..127
  const int l = threadIdx.x & 63;
  const size_t ob = (size_t)row * D_;
  if (row >= B_) {
    #pragma unroll
    for (int j = 0; j < 12; j++) out[ob + j*64 + l] = 0;
    return;
  }
  const float* zr = z + (size_t)row * NT_ * D_;
  float xv[12];
  float s = 0.f;
  #pragma unroll
  for (int j = 0; j < 12; j++) { xv[j] = zr[j*64 + l]; s += xv[j]; }
  #pragma unroll
  for (int m = 1; m < 64; m <<= 1) s += __shfl_xor(s, m, 64);
  const float mean = s * (1.0f / 768.0f);
  float ss = 0.f;
  #pragma unroll
  for (int j = 0; j < 12; j++) { const float d = xv[j] - mean; ss += d * d; }
  #pragma unroll
  for (int m = 1; m < 64; m <<= 1) ss += __shfl_xor(ss, m, 64);
  const float rinv = rsqrtf(ss * (1.0f / 768.0f) + 1e-5f);
  #pragma unroll
  for (int j = 0; j < 12; j++) {
    const int cidx = j*64 + l;
    out[ob + cidx] = f2bf((xv[j] - mean) * rinv * w[cidx] + b[cidx]);
  }
}

// ---------------------------------------------------------------------------
// MFMA per-token head-axis attention (round-3 proven).
// ---------------------------------------------------------------------------
__global__ __launch_bounds__(256) void attn_k(const u16* __restrict__ qkv,
                                              u16* __restrict__ o)
{
  const int tok = (blockIdx.x * 256 + threadIdx.x) >> 6;
  const int l  = threadIdx.x & 63;
  const int g  = l >> 4, li = l & 15;
  const size_t rb = (size_t)tok * (3 * D_);

  f32x4 s = {0.f, 0.f, 0.f, 0.f};
  #pragma unroll
  for (int kt = 0; kt < 2; kt++) {
    const bf16x8 ka = *(const bf16x8*)(qkv + rb + D_ + li*64 + g*8 + kt*32);
    const bf16x8 qb = *(const bf16x8*)(qkv + rb +      li*64 + g*8 + kt*32);
    s = __builtin_amdgcn_mfma_f32_16x16x32_bf16(ka, qb, s, 0, 0, 0);
  }

  float sv[4];
  #pragma unroll
  for (int r2 = 0; r2 < 4; r2++) sv[r2] = s[r2] * 0.125f;
  float mx = (g < 3) ? fmaxf(fmaxf(sv[0], sv[1]), fmaxf(sv[2], sv[3])) : -1e30f;
  mx = fmaxf(mx, __shfl_xor(mx, 16, 64));
  mx = fmaxf(mx, __shfl_xor(mx, 32, 64));
  float p[4], den = 0.f;
  #pragma unroll
  for (int r2 = 0; r2 < 4; r2++) {
    p[r2] = (g < 3) ? __expf(sv[r2] - mx) : 0.f;
    den += p[r2];
  }
  den += __shfl_xor(den, 16, 64);
  den += __shfl_xor(den, 32, 64);
  const float rden = 1.0f / den;
  #pragma unroll
  for (int r2 = 0; r2 < 4; r2++) p[r2] *= rden;

  const u32 pk01 = ((u32)f2bf(p[1]) << 16) | f2bf(p[0]);
  const u32 pk23 = ((u32)f2bf(p[3]) << 16) | f2bf(p[2]);

  const int srcA = (li + (g << 5)) & 63;
  const int srcB = (srcA + 16) & 63;
  u32 b0 = (u32)__shfl((int)pk01, srcA, 64);
  u32 b1 = (u32)__shfl((int)pk23, srcA, 64);
  u32 b2 = (u32)__shfl((int)pk01, srcB, 64);
  u32 b3 = (u32)__shfl((int)pk23, srcB, 64);
  if (g >= 2) { b0 = 0; b1 = 0; b2 = 0; b3 = 0; }
  union { u32 u[4]; bf16x8 v; } pb;
  pb.u[0] = b0; pb.u[1] = b1; pb.u[2] = b2; pb.u[3] = b3;

  const size_t ob = (size_t)tok * D_;
  #pragma unroll
  for (int t = 0; t < 4; t++) {
    union { u16 a[8]; bf16x8 v; } va;
    #pragma unroll
    for (int jp = 0; jp < 8; jp++) {
      const int j = g * 8 + jp;
      va.a[jp] = (j < 12) ? qkv[rb + 2*D_ + j*64 + t*16 + li] : (u16)0;
    }
    f32x4 oac = {0.f, 0.f, 0.f, 0.f};
    oac = __builtin_amdgcn_mfma_f32_16x16x32_bf16(va.v, pb.v, oac, 0, 0, 0);
    if (li < 12) {
      ushort4 ov;
      ov.x = f2bf(oac[0]); ov.y = f2bf(oac[1]);
      ov.z = f2bf(oac[2]); ov.w = f2bf(oac[3]);
      *(ushort4*)(o + ob + li*64 + t*16 + g*4) = ov;
    }
  }
}

// ---------------------------------------------------------------------------
extern "C" void kernel_launch(void* const* d_in, const int* in_sizes, int n_in,
                              void* d_out, int out_size, void* d_ws, size_t ws_size,
                              hipStream_t stream)
{
  const float* x    = (const float*)d_in[0];
  const float* ce   = (const float*)d_in[1];
  const float* pe   = (const float*)d_in[2];
  const float* pw   = (const float*)d_in[3];
  const float* pb   = (const float*)d_in[4];
  const float* qkvw = (const float*)d_in[5];
  const float* qkvb = (const float*)d_in[6];
  const float* topw = (const float*)d_in[7];
  const float* topb = (const float*)d_in[8];
  const float* l1w  = (const float*)d_in[9];
  const float* l1b  = (const float*)d_in[10];
  const float* l2w  = (const float*)d_in[11];
  const float* l2b  = (const float*)d_in[12];
  const float* w1   = (const float*)d_in[13];
  const float* b1   = (const float*)d_in[14];
  const float* w2   = (const float*)d_in[15];
  const float* b2   = (const float*)d_in[16];
  const float* l3w  = (const float*)d_in[17];
  const float* l3b  = (const float*)d_in[18];
  const float* hw1  = (const float*)d_in[19];
  const float* hb1  = (const float*)d_in[20];
  const float* hw2  = (const float*)d_in[21];
  const float* hb2  = (const float*)d_in[22];

  char* ws = (char*)d_ws;
  constexpr size_t SZ_Z  = (size_t)MPAD2 * D_ * 4;
  constexpr size_t SZ_HB = (size_t)MPAD2 * D_ * 2;
  constexpr size_t SZ_QM = (size_t)MPAD2 * DM_ * 2;
  constexpr size_t SZ_WB = (size_t)DM_ * 1024 * 2;
  constexpr size_t SZ_YB = (size_t)128 * D_ * 2;
  float* z  = (float*)ws;
  u16*   hb = (u16*)(ws + SZ_Z);
  u16*   qm = (u16*)(ws + SZ_Z + SZ_HB);
  u16*   wb = (u16*)(ws + SZ_Z + SZ_HB + SZ_QM);
  u16*   yb = (u16*)(ws + SZ_Z + SZ_HB + SZ_QM + SZ_WB);
  u16*   t1 = (u16*)(ws + SZ_Z + SZ_HB + SZ_QM + SZ_WB + SZ_YB);

  const dim3 blk(256);
  const dim3 wblk(32, 8);
  const int MT = MPAD2 / 128;   // 290

  // Patch embedding
  patchify_k<<<B_ * NP_, blk, 0, stream>>>(x, hb);
  wconv_k<<<dim3(D_/32, D_/32), wblk, 0, stream>>>(pw, wb, D_, D_);
  gemmW_k<4><<<6*MT, blk, 0, stream>>>(hb, wb, pb, nullptr, z, D_, D_, 6, 0, 0);
  posecls_k<<<MREAL, blk, 0, stream>>>(z, ce, pe);

  for (int i = 0; i < NL_; i++) {
    ln_k<<<MPAD2/4, blk, 0, stream>>>(z, l1w + i*D_, l1b + i*D_, hb);
    wconv_k<<<dim3(3*D_/32, D_/32), wblk, 0, stream>>>(qkvw + (size_t)i*D_*3*D_, wb, D_, 3*D_);
    gemmW_k<0><<<18*MT, blk, 0, stream>>>(hb, wb, qkvb + i*3*D_, nullptr, qm, D_, 3*D_, 18, 0, 0);
    attn_k<<<MREAL/4, blk, 0, stream>>>(qm, hb);
    wconv_k<<<dim3(D_/32, D_/32), wblk, 0, stream>>>(topw + (size_t)i*D_*D_, wb, D_, D_);
    gemmW_k<1><<<6*MT, blk, 0, stream>>>(hb, wb, topb + i*D_, z, z, D_, D_, 6, 0, 0);
    ln_k<<<MPAD2/4, blk, 0, stream>>>(z, l2w + i*D_, l2b + i*D_, hb);
    wconv_k<<<dim3(DM_/32, D_/32), wblk, 0, stream>>>(w1 + (size_t)i*D_*DM_, wb, D_, DM_);
    gemmW_k<2><<<24*MT, blk, 0, stream>>>(hb, wb, b1 + i*DM_, nullptr, qm, D_, DM_, 24, 0, 0);
    wconv_k<<<dim3(D_/32, DM_/32), wblk, 0, stream>>>(w2 + (size_t)i*DM_*D_, wb, DM_, D_);
    gemmW_k<3><<<6*MT, blk, 0, stream>>>(qm, wb, b2 + i*D_, z, z, DM_, D_, 6, 0, 0);
  }

  // Head: LN(cls) -> MLP with gelu after both linears (M=128 -> 1 bm tile)
  lncls_k<<<32, blk, 0, stream>>>(z, l3w, l3b, yb);
  wconv_k<<<dim3(DM_/32, D_/32), wblk, 0, stream>>>(hw1, wb, D_, DM_);
  gemmW_k<2><<<24, blk, 0, stream>>>(yb, wb, hb1, nullptr, t1, D_, DM_, 24, 0, 0);
  wconv_k<<<dim3(1024/32, DM_/32), wblk, 0, stream>>>(hw2, wb, DM_, NC_);
  gemmW_k<5><<<8, blk, 0, stream>>>(t1, wb, hb2, nullptr, (float*)d_out, DM_, 1024, 8, B_, NC_);
}

// Round 10
// 12024.774 us; speedup vs baseline: 1.2342x; 1.2342x over previous
//
#include <hip/hip_runtime.h>

typedef unsigned short u16;
typedef unsigned int u32;
typedef __bf16 bf16x8 __attribute__((ext_vector_type(8)));
typedef float f32x4 __attribute__((ext_vector_type(4)));

#define D_    768
#define DM_   3072
#define NL_   12
#define NT_   577
#define NP_   576
#define B_    64
#define MREAL (B_*NT_)      /* 36928 */
#define MPAD2 37120         /* 145*256 */
#define NC_   1000
#define IMG_  384

__device__ __forceinline__ float bf2f(u16 v){
  union { unsigned u; float f; } c; c.u = ((unsigned)v) << 16; return c.f;
}
__device__ __forceinline__ u16 f2bf(float f){
  union { float f; unsigned u; } c; c.f = f;
  unsigned r = c.u + 0x7FFFu + ((c.u >> 16) & 1u);
  return (u16)(r >> 16);
}
__device__ __forceinline__ float gelu_f(float x){
  return 0.5f * x * (1.0f + erff(x * 0.70710678118654752f));
}
__device__ __forceinline__ void gload16(const void* g, void* l){
  __builtin_amdgcn_global_load_lds((const __attribute__((address_space(1))) void*)g,
                                   (__attribute__((address_space(3))) void*)l, 16, 0, 0);
}
#define SB_ __builtin_amdgcn_sched_barrier(0)

// ---------------------------------------------------------------------------
// Packed-A GEMM: A in fragment-packed layout [miTile][kt][lane64][8] (bf16),
// B^T [N][K] staged in LDS (dbuf 2x32KiB, counted vmcnt). 256x256 tile,
// 8 waves (2Mx4N). A-frags = direct global_load_dwordx4 (coalesced 1KB/wave),
// double-buffered per K-half into just-freed registers. LDS traffic = B only
// (96KB/K-tile vs 256KB all-LDS) -> LDS-BW ceiling lifts 27% -> ~72%.
// Ledger (per wave, issue order): [B(t):4][Ae(t):8][Ao(t):8] at tile entry;
// top stages B(t+1):4 -> vmcnt(20) retires exactly B(t). A-reg deps are
// compiler-managed (plain VGPR loads). EPI: 0=bf16 bias, 2=bf16 gelu(bias)
// ---------------------------------------------------------------------------
template<int EPI>
__global__ __launch_bounds__(512, 1) void gemmPA_k(
    const u16* __restrict__ Apk, const u16* __restrict__ Bt,
    const float* __restrict__ bias,
    void* __restrict__ outv, int K, int ldo, int nbn)
{
  __shared__ u16 Bs[2][16384];   // 2 x 256rows x 64k
  const int tid = threadIdx.x;
  const int l   = tid & 63;
  const int wid = tid >> 6;
  const int wm  = wid >> 2, wn = wid & 3;
  const int lrow = l & 15;

  const int nwg = gridDim.x;
  const int q = nwg >> 3, r = nwg & 7;
  const int xcd = blockIdx.x & 7, o = blockIdx.x >> 3;
  const int wg = (xcd < r ? xcd * (q + 1) : r * (q + 1) + (xcd - r) * q) + o;
  const int bm = wg / nbn, bn = wg % nbn;

  // B staging (proven pair: swizzled source + swizzled read)
  const int cs8 = ((tid & 7) ^ ((tid >> 3) & 7)) * 8;
  const int rb  = tid >> 3;                       // 0..63
  const u16* bP[4];
  #pragma unroll
  for (int i = 0; i < 4; i++)
    bP[i] = Bt + (size_t)(bn*256 + rb + 64*i) * K + cs8;
  const int ldst = tid * 8;

  // A packed base (includes lane offset)
  const int KT = K >> 5;                          // K/32 chunks
  const u16* aBase = Apk + (size_t)(bm*16 + wm*8) * KT * 512 + (size_t)l * 8;

  const int sw  = (lrow & 7) << 4;
  const int g16 = (l >> 4) << 4;

  f32x4 acc[8][4];
  #pragma unroll
  for (int i = 0; i < 8; i++)
    #pragma unroll
    for (int j = 0; j < 4; j++) acc[i][j] = {0.f, 0.f, 0.f, 0.f};

  const int nk = K >> 6;

  // prologue: stage B(0); load A(0,kk0)->Ae, A(0,kk1)->Ao
  #pragma unroll
  for (int i = 0; i < 4; i++) { gload16(bP[i], &Bs[0][ldst + i*4096]); bP[i] += 64; }
  bf16x8 Ae[8], Ao[8];
  #pragma unroll
  for (int mi = 0; mi < 8; mi++) Ae[mi] = *(const bf16x8*)(aBase + ((size_t)mi*KT + 0)*512);
  #pragma unroll
  for (int mi = 0; mi < 8; mi++) Ao[mi] = *(const bf16x8*)(aBase + ((size_t)mi*KT + 1)*512);

  for (int t = 0; t < nk; ++t) {
    const int cur = t & 1;
    const bool pre = (t + 1 < nk);
    if (pre) {
      #pragma unroll
      for (int i = 0; i < 4; i++) { gload16(bP[i], &Bs[cur^1][ldst + i*4096]); bP[i] += 64; }
    }
    SB_;
    if (pre) asm volatile("s_waitcnt vmcnt(20)" ::: "memory");
    else     asm volatile("s_waitcnt vmcnt(16)" ::: "memory");
    SB_;
    __builtin_amdgcn_s_barrier();
    SB_;
    const char* Bb = (const char*)&Bs[cur][0];
    bf16x8 bfr[4];
    // kk = 0 (uses Ae)
    #pragma unroll
    for (int ni = 0; ni < 4; ni++)
      bfr[ni] = *(const bf16x8*)(Bb + ((wn*64 + ni*16 + lrow) << 7) + (g16 ^ sw));
    asm volatile("s_waitcnt lgkmcnt(0)" ::: "memory");
    SB_;
    __builtin_amdgcn_s_setprio(1);
    #pragma unroll
    for (int mi = 0; mi < 8; mi++)
      #pragma unroll
      for (int ni = 0; ni < 4; ni++)
        acc[mi][ni] = __builtin_amdgcn_mfma_f32_16x16x32_bf16(Ae[mi], bfr[ni], acc[mi][ni], 0, 0, 0);
    __builtin_amdgcn_s_setprio(0);
    SB_;
    if (pre) {
      #pragma unroll
      for (int mi = 0; mi < 8; mi++)
        Ae[mi] = *(const bf16x8*)(aBase + ((size_t)mi*KT + 2*(t+1))*512);
    }
    // kk = 1 (uses Ao)
    #pragma unroll
    for (int ni = 0; ni < 4; ni++)
      bfr[ni] = *(const bf16x8*)(Bb + ((wn*64 + ni*16 + lrow) << 7) + ((64 | g16) ^ sw));
    asm volatile("s_waitcnt lgkmcnt(0)" ::: "memory");
    SB_;
    __builtin_amdgcn_s_setprio(1);
    #pragma unroll
    for (int mi = 0; mi < 8; mi++)
      #pragma unroll
      for (int ni = 0; ni < 4; ni++)
        acc[mi][ni] = __builtin_amdgcn_mfma_f32_16x16x32_bf16(Ao[mi], bfr[ni], acc[mi][ni], 0, 0, 0);
    __builtin_amdgcn_s_setprio(0);
    SB_;
    if (pre) {
      #pragma unroll
      for (int mi = 0; mi < 8; mi++)
        Ao[mi] = *(const bf16x8*)(aBase + ((size_t)mi*KT + 2*(t+1) + 1)*512);
    }
    SB_;
    __builtin_amdgcn_s_barrier();
    SB_;
  }

  const int orow0 = bm*256 + wm*128;
  const int ocol0 = bn*256 + wn*64;
  #pragma unroll
  for (int mi = 0; mi < 8; mi++) {
    #pragma unroll
    for (int ni = 0; ni < 4; ni++) {
      const int col = ocol0 + ni*16 + (l & 15);
      const float bv = bias[col];
      #pragma unroll
      for (int r2 = 0; r2 < 4; r2++) {
        const int row = orow0 + mi*16 + (l >> 4)*4 + r2;
        const float v = acc[mi][ni][r2] + bv;
        const size_t idx = (size_t)row * ldo + col;
        if constexpr (EPI == 0) ((u16*)outv)[idx] = f2bf(v);
        else if constexpr (EPI == 2) ((u16*)outv)[idx] = f2bf(gelu_f(v));
      }
    }
  }
}

// ---------------------------------------------------------------------------
// 256x256 GEMM, 4-phase split (round-5 proven best) — for pe/top/mlp2.
// EPI: 1=f32 bias+res, 3=f32 gelu(bias)+res, 4=f32 bias
// ---------------------------------------------------------------------------
template<int EPI>
__global__ __launch_bounds__(512, 1) void gemm256_k(
    const u16* __restrict__ A, const u16* __restrict__ Bt,
    const float* __restrict__ bias, const float* __restrict__ res,
    void* __restrict__ outv, int K, int ldo, int nbn)
{
  __shared__ u16 lds[2][2][256*64];
  const int tid = threadIdx.x;
  const int l   = tid & 63;
  const int wid = tid >> 6;
  const int wm  = wid >> 2, wn = wid & 3;
  const int lrow = l & 15;

  const int nwg = gridDim.x;
  const int q = nwg >> 3, r = nwg & 7;
  const int xcd = blockIdx.x & 7, o = blockIdx.x >> 3;
  const int wg = (xcd < r ? xcd * (q + 1) : r * (q + 1) + (xcd - r) * q) + o;
  const int bm = wg / nbn, bn = wg % nbn;

  const int cs8 = ((tid & 7) ^ ((tid >> 3) & 7)) * 8;
  const int rb  = tid >> 3;
  const u16* aP[4]; const u16* bP[4];
  #pragma unroll
  for (int i = 0; i < 4; i++) {
    aP[i] = A  + (size_t)(bm*256 + rb + 64*i) * K + cs8;
    bP[i] = Bt + (size_t)(bn*256 + rb + 64*i) * K + cs8;
  }
  const int ldst = tid * 8;

  f32x4 acc[8][4];
  #pragma unroll
  for (int i = 0; i < 8; i++)
    #pragma unroll
    for (int j = 0; j < 4; j++) acc[i][j] = {0.f, 0.f, 0.f, 0.f};

  const int nk = K >> 6;
  #pragma unroll
  for (int i = 0; i < 4; i++) {
    gload16(aP[i], &lds[0][0][ldst + i*4096]);
    gload16(bP[i], &lds[0][1][ldst + i*4096]);
    aP[i] += 64; bP[i] += 64;
  }

  const int sw  = (lrow & 7) << 4;
  const int g16 = (l >> 4) << 4;

  for (int t = 0; t < nk; ++t) {
    const int cur = t & 1;
    const bool pre = (t + 1 < nk);
    u16* dA = &lds[cur^1][0][0];
    u16* dB = &lds[cur^1][1][0];

    if (pre) {
      gload16(aP[0], dA + ldst);
      gload16(aP[1], dA + ldst + 4096);
    }
    SB_;
    if (pre) asm volatile("s_waitcnt vmcnt(2)" ::: "memory");
    else     asm volatile("s_waitcnt vmcnt(0)" ::: "memory");
    SB_;
    __builtin_amdgcn_s_barrier();
    SB_;

    const char* As_ = (const char*)&lds[cur][0][0];
    const char* Bs_ = (const char*)&lds[cur][1][0];
    bf16x8 af[4], bfr[4];

    {
      const int kb = g16;
      #pragma unroll
      for (int ni = 0; ni < 4; ni++)
        bfr[ni] = *(const bf16x8*)(Bs_ + ((wn*64 + ni*16 + lrow) << 7) + (kb ^ sw));
      #pragma unroll
      for (int mi = 0; mi < 4; mi++)
        af[mi] = *(const bf16x8*)(As_ + ((wm*128 + mi*16 + lrow) << 7) + (kb ^ sw));
      if (pre) {
        gload16(aP[2], dA + ldst + 8192);
        gload16(aP[3], dA + ldst + 12288);
      }
      asm volatile("s_waitcnt lgkmcnt(0)" ::: "memory");
      SB_;
      __builtin_amdgcn_s_setprio(1);
      #pragma unroll
      for (int mi = 0; mi < 4; mi++)
        #pragma unroll
        for (int ni = 0; ni < 4; ni++)
          acc[mi][ni] = __builtin_amdgcn_mfma_f32_16x16x32_bf16(af[mi], bfr[ni], acc[mi][ni], 0, 0, 0);
      __builtin_amdgcn_s_setprio(0);
      SB_;
      __builtin_amdgcn_s_barrier();
      SB_;
    }
    {
      const int kb = g16;
      #pragma unroll
      for (int mi = 0; mi < 4; mi++)
        af[mi] = *(const bf16x8*)(As_ + ((wm*128 + (mi+4)*16 + lrow) << 7) + (kb ^ sw));
      if (pre) {
        gload16(bP[0], dB + ldst);
        gload16(bP[1], dB + ldst + 4096);
      }
      asm volatile("s_waitcnt lgkmcnt(0)" ::: "memory");
      SB_;
      __builtin_amdgcn_s_setprio(1);
      #pragma unroll
      for (int mi = 0; mi < 4; mi++)
        #pragma unroll
        for (int ni = 0; ni < 4; ni++)
          acc[mi+4][ni] = __builtin_amdgcn_mfma_f32_16x16x32_bf16(af[mi], bfr[ni], acc[mi+4][ni], 0, 0, 0);
      __builtin_amdgcn_s_setprio(0);
      SB_;
      __builtin_amdgcn_s_barrier();
      SB_;
    }
    {
      const int kb = 64 | g16;
      #pragma unroll
      for (int ni = 0; ni < 4; ni++)
        bfr[ni] = *(const bf16x8*)(Bs_ + ((wn*64 + ni*16 + lrow) << 7) + (kb ^ sw));
      #pragma unroll
      for (int mi = 0; mi < 4; mi++)
        af[mi] = *(const bf16x8*)(As_ + ((wm*128 + mi*16 + lrow) << 7) + (kb ^ sw));
      if (pre) {
        gload16(bP[2], dB + ldst + 8192);
        gload16(bP[3], dB + ldst + 12288);
      }
      asm volatile("s_waitcnt lgkmcnt(0)" ::: "memory");
      SB_;
      __builtin_amdgcn_s_setprio(1);
      #pragma unroll
      for (int mi = 0; mi < 4; mi++)
        #pragma unroll
        for (int ni = 0; ni < 4; ni++)
          acc[mi][ni] = __builtin_amdgcn_mfma_f32_16x16x32_bf16(af[mi], bfr[ni], acc[mi][ni], 0, 0, 0);
      __builtin_amdgcn_s_setprio(0);
      SB_;
      __builtin_amdgcn_s_barrier();
      SB_;
    }
    {
      const int kb = 64 | g16;
      #pragma unroll
      for (int mi = 0; mi < 4; mi++)
        af[mi] = *(const bf16x8*)(As_ + ((wm*128 + (mi+4)*16 + lrow) << 7) + (kb ^ sw));
      asm volatile("s_waitcnt lgkmcnt(0)" ::: "memory");
      SB_;
      __builtin_amdgcn_s_setprio(1);
      #pragma unroll
      for (int mi = 0; mi < 4; mi++)
        #pragma unroll
        for (int ni = 0; ni < 4; ni++)
          acc[mi+4][ni] = __builtin_amdgcn_mfma_f32_16x16x32_bf16(af[mi], bfr[ni], acc[mi+4][ni], 0, 0, 0);
      __builtin_amdgcn_s_setprio(0);
      SB_;
      __builtin_amdgcn_s_barrier();
      SB_;
    }
    if (pre) {
      #pragma unroll
      for (int i = 0; i < 4; i++) { aP[i] += 64; bP[i] += 64; }
    }
  }

  const int orow0 = bm*256 + wm*128;
  const int ocol0 = bn*256 + wn*64;
  #pragma unroll
  for (int mi = 0; mi < 8; mi++) {
    #pragma unroll
    for (int ni = 0; ni < 4; ni++) {
      const int col = ocol0 + ni*16 + (l & 15);
      const float bv = bias[col];
      #pragma unroll
      for (int r2 = 0; r2 < 4; r2++) {
        const int row = orow0 + mi*16 + (l >> 4)*4 + r2;
        const float v = acc[mi][ni][r2] + bv;
        const size_t idx = (size_t)row * ldo + col;
        if constexpr (EPI == 1) ((float*)outv)[idx] = v + res[idx];
        else if constexpr (EPI == 3) ((float*)outv)[idx] = gelu_f(v) + res[idx];
        else if constexpr (EPI == 4) ((float*)outv)[idx] = v;
      }
    }
  }
}

// ---------------------------------------------------------------------------
// 128x128 single-buffered GEMM — tiny head GEMMs (M=128).
// EPI: 2=bf16 gelu(bias), 5=f32 gelu(bias) bounded store [Ms,Ns]
// ---------------------------------------------------------------------------
template<int EPI>
__global__ __launch_bounds__(256) void gemm_k(
    const u16* __restrict__ A, const u16* __restrict__ Bt,
    const float* __restrict__ bias, const float* __restrict__ res,
    void* __restrict__ outv, int K, int ldo, int nbn, int Ms, int Ns)
{
  __shared__ u16 As[128*64];
  __shared__ u16 Bs[128*64];
  const int tid = threadIdx.x;
  const int l   = tid & 63;
  const int w   = tid >> 6;
  const int wm  = w >> 1, wn = w & 1;
  const int lrow = l & 15;

  const int nwg = gridDim.x;
  const int q = nwg >> 3, r = nwg & 7;
  const int xcd = blockIdx.x & 7, o = blockIdx.x >> 3;
  const int wg = (xcd < r ? xcd * (q + 1) : r * (q + 1) + (xcd - r) * q) + o;
  const int bm = wg / nbn, bn = wg % nbn;

  const int cs8 = ((tid & 7) ^ ((tid >> 3) & 7)) * 8;
  const int rb  = tid >> 3;
  const size_t abase = (size_t)bm * 128 * K;
  const size_t bbase = (size_t)bn * 128 * K;
  size_t aoff[4], boff[4];
  #pragma unroll
  for (int i = 0; i < 4; i++) {
    aoff[i] = abase + (size_t)(rb + 32 * i) * K + cs8;
    boff[i] = bbase + (size_t)(rb + 32 * i) * K + cs8;
  }

  const int colA = (l >> 4) << 4;
  const int sw   = (lrow & 7) << 4;

  f32x4 acc[4][4];
  #pragma unroll
  for (int i = 0; i < 4; i++)
    #pragma unroll
    for (int j = 0; j < 4; j++) acc[i][j] = {0.f, 0.f, 0.f, 0.f};

  const int nk = K >> 6;
  for (int kt = 0; kt < nk; ++kt) {
    const int koff = kt * 64;
    #pragma unroll
    for (int i = 0; i < 4; i++) {
      gload16(A  + aoff[i] + koff, As + tid * 8 + i * 2048);
      gload16(Bt + boff[i] + koff, Bs + tid * 8 + i * 2048);
    }
    __syncthreads();
    #pragma unroll
    for (int kk = 0; kk < 2; kk++) {
      bf16x8 af[4], bfr[4];
      #pragma unroll
      for (int mi = 0; mi < 4; mi++)
        af[mi] = *(const bf16x8*)((const char*)As +
                  ((wm*64 + mi*16 + lrow) << 7) + (((kk << 6) | colA) ^ sw));
      #pragma unroll
      for (int ni = 0; ni < 4; ni++)
        bfr[ni] = *(const bf16x8*)((const char*)Bs +
                  ((wn*64 + ni*16 + lrow) << 7) + (((kk << 6) | colA) ^ sw));
      #pragma unroll
      for (int mi = 0; mi < 4; mi++)
        #pragma unroll
        for (int ni = 0; ni < 4; ni++)
          acc[mi][ni] = __builtin_amdgcn_mfma_f32_16x16x32_bf16(af[mi], bfr[ni], acc[mi][ni], 0, 0, 0);
    }
    __syncthreads();
  }

  const int orow0 = bm*128 + wm*64;
  const int ocol0 = bn*128 + wn*64;
  #pragma unroll
  for (int mi = 0; mi < 4; mi++) {
    #pragma unroll
    for (int ni = 0; ni < 4; ni++) {
      #pragma unroll
      for (int r2 = 0; r2 < 4; r2++) {
        const int row = orow0 + mi*16 + (l >> 4)*4 + r2;
        const int col = ocol0 + ni*16 + (l & 15);
        float bv;
        if constexpr (EPI == 5) bv = (col < Ns) ? bias[col] : 0.f;
        else bv = bias[col];
        const float v = acc[mi][ni][r2] + bv;
        const size_t idx = (size_t)row * ldo + col;
        if constexpr (EPI == 2) ((u16*)outv)[idx] = f2bf(gelu_f(v));
        else if constexpr (EPI == 5) {
          if (row < Ms && col < Ns) ((float*)outv)[(size_t)row * Ns + col] = gelu_f(v);
        }
      }
    }
  }
}

// ---------------------------------------------------------------------------
__global__ void wconv_k(const float* __restrict__ W, u16* __restrict__ Wt,
                        int K, int N)
{
  __shared__ float tile[32][33];
  const int n0 = blockIdx.x * 32, k0 = blockIdx.y * 32;
  const int tx = threadIdx.x, ty = threadIdx.y;
  #pragma unroll
  for (int r = 0; r < 4; r++) {
    const int kk = k0 + ty + r*8;
    const int nn = n0 + tx;
    tile[ty + r*8][tx] = (nn < N) ? W[(size_t)kk * N + nn] : 0.f;
  }
  __syncthreads();
  #pragma unroll
  for (int r = 0; r < 4; r++) {
    const int nn = n0 + ty + r*8;
    Wt[(size_t)nn * K + k0 + tx] = f2bf(tile[tx][ty + r*8]);
  }
}

// ---------------------------------------------------------------------------
__global__ void patchify_k(const float* __restrict__ x, u16* __restrict__ hb)
{
  const int blk = blockIdx.x;
  const int b = blk / NP_, p = blk % NP_;
  const int pr = p / 24, pc = p % 24;
  const size_t row = (size_t)b * NT_ + 1 + p;
  #pragma unroll
  for (int u = 0; u < 3; u++) {
    const int j  = threadIdx.x + u * 256;
    const int c  = j >> 8, ph = (j >> 4) & 15, pw = j & 15;
    const float v = x[((size_t)(b*3 + c) * IMG_ + pr*16 + ph) * IMG_ + pc*16 + pw];
    hb[row * D_ + j] = f2bf(v);
  }
}

__global__ void posecls_k(float* __restrict__ z, const float* __restrict__ ce,
                          const float* __restrict__ pe)
{
  const int row = blockIdx.x;
  const int t = row % NT_;
  const size_t base = (size_t)row * D_;
  #pragma unroll
  for (int u = 0; u < 3; u++) {
    const int j = threadIdx.x + u * 256;
    if (t == 0) z[base + j] = ce[j] + pe[j];
    else        z[base + j] += pe[(size_t)t * D_ + j];
  }
}

// ---------------------------------------------------------------------------
// LayerNorm -> fragment-packed bf16 output [miTile][kt=24][lane64][8].
// Block = 256 thr handles 16 rows (one mi tile). Pass 1: stats (wave w does
// rows w*4..w*4+3, as the proven per-wave LN). Pass 2: packed writes, fully
// coalesced (consecutive tid -> consecutive 16B chunks).
// ---------------------------------------------------------------------------
__global__ void ln_pk(const float* __restrict__ z, const float* __restrict__ w,
                      const float* __restrict__ b, u16* __restrict__ out)
{
  __shared__ float st[16][2];
  const int blk = blockIdx.x;
  const int tid = threadIdx.x;
  const int l = tid & 63, w4 = tid >> 6;

  for (int rr = 0; rr < 4; rr++) {
    const int lr = w4*4 + rr;
    const float4* zr = (const float4*)(z + ((size_t)blk*16 + lr) * D_);
    float4 xq[3];
    float s = 0.f;
    #pragma unroll
    for (int j = 0; j < 3; j++) {
      xq[j] = zr[j*64 + l];
      s += xq[j].x + xq[j].y + xq[j].z + xq[j].w;
    }
    #pragma unroll
    for (int m = 1; m < 64; m <<= 1) s += __shfl_xor(s, m, 64);
    const float mean = s * (1.0f / 768.0f);
    float ss = 0.f;
    #pragma unroll
    for (int j = 0; j < 3; j++) {
      const float dx = xq[j].x-mean, dy = xq[j].y-mean, dz = xq[j].z-mean, dw = xq[j].w-mean;
      ss += dx*dx + dy*dy + dz*dz + dw*dw;
    }
    #pragma unroll
    for (int m = 1; m < 64; m <<= 1) ss += __shfl_xor(ss, m, 64);
    if (l == 0) {
      st[lr][0] = mean;
      st[lr][1] = rsqrtf(ss * (1.0f / 768.0f) + 1e-5f);
    }
  }
  __syncthreads();

  #pragma unroll
  for (int i = 0; i < 6; i++) {
    const int c = tid + i*256;              // 0..1535 = kt*64 + lane
    const int kt = c >> 6, lane = c & 63;
    const int lr = lane & 15, g = (lane >> 4);
    const int k0 = kt*32 + g*8;
    const float* zp = z + ((size_t)blk*16 + lr) * D_ + k0;
    const float4 a0 = *(const float4*)zp;
    const float4 a1 = *(const float4*)(zp + 4);
    const float4 w0 = *(const float4*)(w + k0);
    const float4 w1 = *(const float4*)(w + k0 + 4);
    const float4 b0 = *(const float4*)(b + k0);
    const float4 b1 = *(const float4*)(b + k0 + 4);
    const float mean = st[lr][0], rinv = st[lr][1];
    u16 ov[8];
    ov[0] = f2bf((a0.x - mean) * rinv * w0.x + b0.x);
    ov[1] = f2bf((a0.y - mean) * rinv * w0.y + b0.y);
    ov[2] = f2bf((a0.z - mean) * rinv * w0.z + b0.z);
    ov[3] = f2bf((a0.w - mean) * rinv * w0.w + b0.w);
    ov[4] = f2bf((a1.x - mean) * rinv * w1.x + b1.x);
    ov[5] = f2bf((a1.y - mean) * rinv * w1.y + b1.y);
    ov[6] = f2bf((a1.z - mean) * rinv * w1.z + b1.z);
    ov[7] = f2bf((a1.w - mean) * rinv * w1.w + b1.w);
    *(uint4*)(out + ((size_t)(blk*24 + kt)*64 + lane)*8) = *(const uint4*)ov;
  }
}

// Final LN over cls rows -> yb[128][768] bf16 (rows >= 64 zeroed)
__global__ void lncls_k(const float* __restrict__ z, const float* __restrict__ w,
                        const float* __restrict__ b, u16* __restrict__ out)
{
  const int row = blockIdx.x * 4 + (threadIdx.x >> 6);   // 0..127
  const int l = threadIdx.x & 63;
  const size_t ob = (size_t)row * D_;
  if (row >= B_) {
    #pragma unroll
    for (int j = 0; j < 12; j++) out[ob + j*64 + l] = 0;
    return;
  }
  const float* zr = z + (size_t)row * NT_ * D_;
  float xv[12];
  float s = 0.f;
  #pragma unroll
  for (int j = 0; j < 12; j++) { xv[j] = zr[j*64 + l]; s += xv[j]; }
  #pragma unroll
  for (int m = 1; m < 64; m <<= 1) s += __shfl_xor(s, m, 64);
  const float mean = s * (1.0f / 768.0f);
  float ss = 0.f;
  #pragma unroll
  for (int j = 0; j < 12; j++) { const float d = xv[j] - mean; ss += d * d; }
  #pragma unroll
  for (int m = 1; m < 64; m <<= 1) ss += __shfl_xor(ss, m, 64);
  const float rinv = rsqrtf(ss * (1.0f / 768.0f) + 1e-5f);
  #pragma unroll
  for (int j = 0; j < 12; j++) {
    const int cidx = j*64 + l;
    out[ob + cidx] = f2bf((xv[j] - mean) * rinv * w[cidx] + b[cidx]);
  }
}

// ---------------------------------------------------------------------------
// MFMA per-token head-axis attention (round-3 proven).
// ---------------------------------------------------------------------------
__global__ __launch_bounds__(256) void attn_k(const u16* __restrict__ qkv,
                                              u16* __restrict__ o)
{
  const int tok = (blockIdx.x * 256 + threadIdx.x) >> 6;
  const int l  = threadIdx.x & 63;
  const int g  = l >> 4, li = l & 15;
  const size_t rb = (size_t)tok * (3 * D_);

  f32x4 s = {0.f, 0.f, 0.f, 0.f};
  #pragma unroll
  for (int kt = 0; kt < 2; kt++) {
    const bf16x8 ka = *(const bf16x8*)(qkv + rb + D_ + li*64 + g*8 + kt*32);
    const bf16x8 qb = *(const bf16x8*)(qkv + rb +      li*64 + g*8 + kt*32);
    s = __builtin_amdgcn_mfma_f32_16x16x32_bf16(ka, qb, s, 0, 0, 0);
  }

  float sv[4];
  #pragma unroll
  for (int r2 = 0; r2 < 4; r2++) sv[r2] = s[r2] * 0.125f;
  float mx = (g < 3) ? fmaxf(fmaxf(sv[0], sv[1]), fmaxf(sv[2], sv[3])) : -1e30f;
  mx = fmaxf(mx, __shfl_xor(mx, 16, 64));
  mx = fmaxf(mx, __shfl_xor(mx, 32, 64));
  float p[4], den = 0.f;
  #pragma unroll
  for (int r2 = 0; r2 < 4; r2++) {
    p[r2] = (g < 3) ? __expf(sv[r2] - mx) : 0.f;
    den += p[r2];
  }
  den += __shfl_xor(den, 16, 64);
  den += __shfl_xor(den, 32, 64);
  const float rden = 1.0f / den;
  #pragma unroll
  for (int r2 = 0; r2 < 4; r2++) p[r2] *= rden;

  const u32 pk01 = ((u32)f2bf(p[1]) << 16) | f2bf(p[0]);
  const u32 pk23 = ((u32)f2bf(p[3]) << 16) | f2bf(p[2]);

  const int srcA = (li + (g << 5)) & 63;
  const int srcB = (srcA + 16) & 63;
  u32 b0 = (u32)__shfl((int)pk01, srcA, 64);
  u32 b1 = (u32)__shfl((int)pk23, srcA, 64);
  u32 b2 = (u32)__shfl((int)pk01, srcB, 64);
  u32 b3 = (u32)__shfl((int)pk23, srcB, 64);
  if (g >= 2) { b0 = 0; b1 = 0; b2 = 0; b3 = 0; }
  union { u32 u[4]; bf16x8 v; } pb;
  pb.u[0] = b0; pb.u[1] = b1; pb.u[2] = b2; pb.u[3] = b3;

  const size_t ob = (size_t)tok * D_;
  #pragma unroll
  for (int t = 0; t < 4; t++) {
    union { u16 a[8]; bf16x8 v; } va;
    #pragma unroll
    for (int jp = 0; jp < 8; jp++) {
      const int j = g * 8 + jp;
      va.a[jp] = (j < 12) ? qkv[rb + 2*D_ + j*64 + t*16 + li] : (u16)0;
    }
    f32x4 oac = {0.f, 0.f, 0.f, 0.f};
    oac = __builtin_amdgcn_mfma_f32_16x16x32_bf16(va.v, pb.v, oac, 0, 0, 0);
    if (li < 12) {
      ushort4 ov;
      ov.x = f2bf(oac[0]); ov.y = f2bf(oac[1]);
      ov.z = f2bf(oac[2]); ov.w = f2bf(oac[3]);
      *(ushort4*)(o + ob + li*64 + t*16 + g*4) = ov;
    }
  }
}

// ---------------------------------------------------------------------------
extern "C" void kernel_launch(void* const* d_in, const int* in_sizes, int n_in,
                              void* d_out, int out_size, void* d_ws, size_t ws_size,
                              hipStream_t stream)
{
  const float* x    = (const float*)d_in[0];
  const float* ce   = (const float*)d_in[1];
  const float* pe   = (const float*)d_in[2];
  const float* pw   = (const float*)d_in[3];
  const float* pb   = (const float*)d_in[4];
  const float* qkvw = (const float*)d_in[5];
  const float* qkvb = (const float*)d_in[6];
  const float* topw = (const float*)d_in[7];
  const float* topb = (const float*)d_in[8];
  const float* l1w  = (const float*)d_in[9];
  const float* l1b  = (const float*)d_in[10];
  const float* l2w  = (const float*)d_in[11];
  const float* l2b  = (const float*)d_in[12];
  const float* w1   = (const float*)d_in[13];
  const float* b1   = (const float*)d_in[14];
  const float* w2   = (const float*)d_in[15];
  const float* b2   = (const float*)d_in[16];
  const float* l3w  = (const float*)d_in[17];
  const float* l3b  = (const float*)d_in[18];
  const float* hw1  = (const float*)d_in[19];
  const float* hb1  = (const float*)d_in[20];
  const float* hw2  = (const float*)d_in[21];
  const float* hb2  = (const float*)d_in[22];

  char* ws = (char*)d_ws;
  constexpr size_t SZ_Z  = (size_t)MPAD2 * D_ * 4;
  constexpr size_t SZ_HB = (size_t)MPAD2 * D_ * 2;
  constexpr size_t SZ_QM = (size_t)MPAD2 * DM_ * 2;
  constexpr size_t SZ_WB = (size_t)DM_ * 1024 * 2;
  constexpr size_t SZ_YB = (size_t)128 * D_ * 2;
  float* z  = (float*)ws;
  u16*   hb = (u16*)(ws + SZ_Z);
  u16*   qm = (u16*)(ws + SZ_Z + SZ_HB);
  u16*   wb = (u16*)(ws + SZ_Z + SZ_HB + SZ_QM);
  u16*   yb = (u16*)(ws + SZ_Z + SZ_HB + SZ_QM + SZ_WB);
  u16*   t1 = (u16*)(ws + SZ_Z + SZ_HB + SZ_QM + SZ_WB + SZ_YB);

  const dim3 blk(256);
  const dim3 blk5(512);
  const dim3 wblk(32, 8);
  const int MT2 = MPAD2 / 256;  // 145

  // Patch embedding (hb row-major here)
  patchify_k<<<B_ * NP_, blk, 0, stream>>>(x, hb);
  wconv_k<<<dim3(D_/32, D_/32), wblk, 0, stream>>>(pw, wb, D_, D_);
  gemm256_k<4><<<3*MT2, blk5, 0, stream>>>(hb, wb, pb, nullptr, z, D_, D_, 3);
  posecls_k<<<MREAL, blk, 0, stream>>>(z, ce, pe);

  for (int i = 0; i < NL_; i++) {
    ln_pk<<<MPAD2/16, blk, 0, stream>>>(z, l1w + i*D_, l1b + i*D_, hb);   // hb packed
    wconv_k<<<dim3(3*D_/32, D_/32), wblk, 0, stream>>>(qkvw + (size_t)i*D_*3*D_, wb, D_, 3*D_);
    gemmPA_k<0><<<9*MT2, blk5, 0, stream>>>(hb, wb, qkvb + i*3*D_, qm, D_, 3*D_, 9);
    attn_k<<<MREAL/4, blk, 0, stream>>>(qm, hb);                           // hb row-major
    wconv_k<<<dim3(D_/32, D_/32), wblk, 0, stream>>>(topw + (size_t)i*D_*D_, wb, D_, D_);
    gemm256_k<1><<<3*MT2, blk5, 0, stream>>>(hb, wb, topb + i*D_, z, z, D_, D_, 3);
    ln_pk<<<MPAD2/16, blk, 0, stream>>>(z, l2w + i*D_, l2b + i*D_, hb);   // hb packed
    wconv_k<<<dim3(DM_/32, D_/32), wblk, 0, stream>>>(w1 + (size_t)i*D_*DM_, wb, D_, DM_);
    gemmPA_k<2><<<12*MT2, blk5, 0, stream>>>(hb, wb, b1 + i*DM_, qm, D_, DM_, 12);
    wconv_k<<<dim3(D_/32, DM_/32), wblk, 0, stream>>>(w2 + (size_t)i*DM_*D_, wb, DM_, D_);
    gemm256_k<3><<<3*MT2, blk5, 0, stream>>>(qm, wb, b2 + i*D_, z, z, DM_, D_, 3);
  }

  // Head
  lncls_k<<<32, blk, 0, stream>>>(z, l3w, l3b, yb);
  wconv_k<<<dim3(DM_/32, D_/32), wblk, 0, stream>>>(hw1, wb, D_, DM_);
  gemm_k<2><<<24, blk, 0, stream>>>(yb, wb, hb1, nullptr, t1, D_, DM_, 24, 0, 0);
  wconv_k<<<dim3(1024/32, DM_/32), wblk, 0, stream>>>(hw2, wb, DM_, NC_);
  gemm_k<5><<<8, blk, 0, stream>>>(t1, wb, hb2, nullptr, (float*)d_out, DM_, 1024, 8, B_, NC_);
}

// Round 11
// 11964.162 us; speedup vs baseline: 1.2405x; 1.0051x over previous
//
#include <hip/hip_runtime.h>

typedef unsigned short u16;
typedef unsigned int u32;
typedef __bf16 bf16x8 __attribute__((ext_vector_type(8)));
typedef float f32x4 __attribute__((ext_vector_type(4)));
typedef float f32x16 __attribute__((ext_vector_type(16)));

#define D_    768
#define DM_   3072
#define NL_   12
#define NT_   577
#define NP_   576
#define B_    64
#define MREAL (B_*NT_)      /* 36928 */
#define MPAD2 37120         /* 145*256 */
#define NC_   1000
#define IMG_  384

__device__ __forceinline__ float bf2f(u16 v){
  union { unsigned u; float f; } c; c.u = ((unsigned)v) << 16; return c.f;
}
__device__ __forceinline__ u16 f2bf(float f){
  union { float f; unsigned u; } c; c.f = f;
  unsigned r = c.u + 0x7FFFu + ((c.u >> 16) & 1u);
  return (u16)(r >> 16);
}
__device__ __forceinline__ float gelu_f(float x){
  return 0.5f * x * (1.0f + erff(x * 0.70710678118654752f));
}
__device__ __forceinline__ void gload16(const void* g, void* l){
  __builtin_amdgcn_global_load_lds((const __attribute__((address_space(1))) void*)g,
                                   (__attribute__((address_space(3))) void*)l, 16, 0, 0);
}
#define SB_ __builtin_amdgcn_sched_barrier(0)

// ---------------------------------------------------------------------------
// 256x256 GEMM, 4-phase split (round-5 proven staging/ledger), MFMA shape
// swapped to 32x32x16. 8 waves (2Mx4N), wave tile 128x64 = 4 mt x 2 nt.
// Phase p = (khalf p>>1, mhalf p&1): 8 MFMA each (2mt x 2nt x 2kk).
// Frag map: A row=l&31, slot=2*kk+(l>>5); B identical (sigma-trick).
// C/D (m74/m101-verified): col=l&31, row=(reg&3)+8*(reg>>2)+4*(l>>5).
// EPI: 0=bf16 bias, 1=f32 bias+res, 2=bf16 gelu(bias), 3=f32 gelu(bias)+res,
//      4=f32 bias
// ---------------------------------------------------------------------------
template<int EPI>
__global__ __launch_bounds__(512, 1) void gemm256_k(
    const u16* __restrict__ A, const u16* __restrict__ Bt,
    const float* __restrict__ bias, const float* __restrict__ res,
    void* __restrict__ outv, int K, int ldo, int nbn)
{
  __shared__ u16 lds[2][2][256*64];
  const int tid = threadIdx.x;
  const int l   = tid & 63;
  const int wid = tid >> 6;
  const int wm  = wid >> 2, wn = wid & 3;
  const int l31 = l & 31;
  const int g2  = l >> 5;

  const int nwg = gridDim.x;
  const int q = nwg >> 3, r = nwg & 7;
  const int xcd = blockIdx.x & 7, o = blockIdx.x >> 3;
  const int wg = (xcd < r ? xcd * (q + 1) : r * (q + 1) + (xcd - r) * q) + o;
  const int bm = wg / nbn, bn = wg % nbn;

  const int cs8 = ((tid & 7) ^ ((tid >> 3) & 7)) * 8;
  const int rb  = tid >> 3;
  const u16* aP[4]; const u16* bP[4];
  #pragma unroll
  for (int i = 0; i < 4; i++) {
    aP[i] = A  + (size_t)(bm*256 + rb + 64*i) * K + cs8;
    bP[i] = Bt + (size_t)(bn*256 + rb + 64*i) * K + cs8;
  }
  const int ldst = tid * 8;

  f32x16 acc[4][2];
  #pragma unroll
  for (int i = 0; i < 4; i++)
    #pragma unroll
    for (int j = 0; j < 2; j++)
      #pragma unroll
      for (int e = 0; e < 16; e++) acc[i][j][e] = 0.f;

  const int nk = K >> 6;
  #pragma unroll
  for (int i = 0; i < 4; i++) {
    gload16(aP[i], &lds[0][0][ldst + i*4096]);
    gload16(bP[i], &lds[0][1][ldst + i*4096]);
    aP[i] += 64; bP[i] += 64;
  }

  const int xk = (l31 & 7) << 4;                 // swizzle XOR key (bytes)

  // row-byte bases (row << 7)
  int arb[4], brb[2];
  #pragma unroll
  for (int mt = 0; mt < 4; mt++) arb[mt] = (wm*128 + mt*32 + l31) << 7;
  #pragma unroll
  for (int nt = 0; nt < 2; nt++) brb[nt] = (wn*64 + nt*32 + l31) << 7;

  for (int t = 0; t < nk; ++t) {
    const int cur = t & 1;
    const bool pre = (t + 1 < nk);
    u16* dA = &lds[cur^1][0][0];
    u16* dB = &lds[cur^1][1][0];

    if (pre) {
      gload16(aP[0], dA + ldst);
      gload16(aP[1], dA + ldst + 4096);
    }
    SB_;
    if (pre) asm volatile("s_waitcnt vmcnt(2)" ::: "memory");
    else     asm volatile("s_waitcnt vmcnt(0)" ::: "memory");
    SB_;
    __builtin_amdgcn_s_barrier();
    SB_;

    const char* As_ = (const char*)&lds[cur][0][0];
    const char* Bs_ = (const char*)&lds[cur][1][0];
    bf16x8 af[4], bfr[4];

    // ---- phase 0: khalf0 (kk=0,1), mt 0-1; B-reads khalf0; stage A q2,q3
    {
      #pragma unroll
      for (int nt = 0; nt < 2; nt++)
        #pragma unroll
        for (int kk = 0; kk < 2; kk++)
          bfr[nt*2+kk] = *(const bf16x8*)(Bs_ + brb[nt] + ((((2*kk + g2) << 4)) ^ xk));
      #pragma unroll
      for (int mt = 0; mt < 2; mt++)
        #pragma unroll
        for (int kk = 0; kk < 2; kk++)
          af[mt*2+kk] = *(const bf16x8*)(As_ + arb[mt] + ((((2*kk + g2) << 4)) ^ xk));
      if (pre) {
        gload16(aP[2], dA + ldst + 8192);
        gload16(aP[3], dA + ldst + 12288);
      }
      asm volatile("s_waitcnt lgkmcnt(0)" ::: "memory");
      SB_;
      __builtin_amdgcn_s_setprio(1);
      #pragma unroll
      for (int mt = 0; mt < 2; mt++)
        #pragma unroll
        for (int nt = 0; nt < 2; nt++)
          #pragma unroll
          for (int kk = 0; kk < 2; kk++)
            acc[mt][nt] = __builtin_amdgcn_mfma_f32_32x32x16_bf16(af[mt*2+kk], bfr[nt*2+kk], acc[mt][nt], 0, 0, 0);
      __builtin_amdgcn_s_setprio(0);
      SB_;
      __builtin_amdgcn_s_barrier();
      SB_;
    }
    // ---- phase 1: khalf0, mt 2-3 (B reused); stage B q0,q1
    {
      #pragma unroll
      for (int mt = 0; mt < 2; mt++)
        #pragma unroll
        for (int kk = 0; kk < 2; kk++)
          af[mt*2+kk] = *(const bf16x8*)(As_ + arb[mt+2] + ((((2*kk + g2) << 4)) ^ xk));
      if (pre) {
        gload16(bP[0], dB + ldst);
        gload16(bP[1], dB + ldst + 4096);
      }
      asm volatile("s_waitcnt lgkmcnt(0)" ::: "memory");
      SB_;
      __builtin_amdgcn_s_setprio(1);
      #pragma unroll
      for (int mt = 0; mt < 2; mt++)
        #pragma unroll
        for (int nt = 0; nt < 2; nt++)
          #pragma unroll
          for (int kk = 0; kk < 2; kk++)
            acc[mt+2][nt] = __builtin_amdgcn_mfma_f32_32x32x16_bf16(af[mt*2+kk], bfr[nt*2+kk], acc[mt+2][nt], 0, 0, 0);
      __builtin_amdgcn_s_setprio(0);
      SB_;
      __builtin_amdgcn_s_barrier();
      SB_;
    }
    // ---- phase 2: khalf1 (kk=2,3), mt 0-1; new B-reads; stage B q2,q3
    {
      #pragma unroll
      for (int nt = 0; nt < 2; nt++)
        #pragma unroll
        for (int kk = 0; kk < 2; kk++)
          bfr[nt*2+kk] = *(const bf16x8*)(Bs_ + brb[nt] + ((((4 + 2*kk + g2) << 4)) ^ xk));
      #pragma unroll
      for (int mt = 0; mt < 2; mt++)
        #pragma unroll
        for (int kk = 0; kk < 2; kk++)
          af[mt*2+kk] = *(const bf16x8*)(As_ + arb[mt] + ((((4 + 2*kk + g2) << 4)) ^ xk));
      if (pre) {
        gload16(bP[2], dB + ldst + 8192);
        gload16(bP[3], dB + ldst + 12288);
      }
      asm volatile("s_waitcnt lgkmcnt(0)" ::: "memory");
      SB_;
      __builtin_amdgcn_s_setprio(1);
      #pragma unroll
      for (int mt = 0; mt < 2; mt++)
        #pragma unroll
        for (int nt = 0; nt < 2; nt++)
          #pragma unroll
          for (int kk = 0; kk < 2; kk++)
            acc[mt][nt] = __builtin_amdgcn_mfma_f32_32x32x16_bf16(af[mt*2+kk], bfr[nt*2+kk], acc[mt][nt], 0, 0, 0);
      __builtin_amdgcn_s_setprio(0);
      SB_;
      __builtin_amdgcn_s_barrier();
      SB_;
    }
    // ---- phase 3: khalf1, mt 2-3; no stage
    {
      #pragma unroll
      for (int mt = 0; mt < 2; mt++)
        #pragma unroll
        for (int kk = 0; kk < 2; kk++)
          af[mt*2+kk] = *(const bf16x8*)(As_ + arb[mt+2] + ((((4 + 2*kk + g2) << 4)) ^ xk));
      asm volatile("s_waitcnt lgkmcnt(0)" ::: "memory");
      SB_;
      __builtin_amdgcn_s_setprio(1);
      #pragma unroll
      for (int mt = 0; mt < 2; mt++)
        #pragma unroll
        for (int nt = 0; nt < 2; nt++)
          #pragma unroll
          for (int kk = 0; kk < 2; kk++)
            acc[mt+2][nt] = __builtin_amdgcn_mfma_f32_32x32x16_bf16(af[mt*2+kk], bfr[nt*2+kk], acc[mt+2][nt], 0, 0, 0);
      __builtin_amdgcn_s_setprio(0);
      SB_;
      __builtin_amdgcn_s_barrier();
      SB_;
    }
    if (pre) {
      #pragma unroll
      for (int i = 0; i < 4; i++) { aP[i] += 64; bP[i] += 64; }
    }
  }

  const int orow0 = bm*256 + wm*128;
  const int ocol0 = bn*256 + wn*64;
  #pragma unroll
  for (int mt = 0; mt < 4; mt++) {
    #pragma unroll
    for (int nt = 0; nt < 2; nt++) {
      const int col = ocol0 + nt*32 + l31;
      const float bv = bias[col];
      #pragma unroll
      for (int reg = 0; reg < 16; reg++) {
        const int row = orow0 + mt*32 + (reg & 3) + 8*(reg >> 2) + 4*g2;
        const float v = acc[mt][nt][reg] + bv;
        const size_t idx = (size_t)row * ldo + col;
        if constexpr (EPI == 0) ((u16*)outv)[idx] = f2bf(v);
        else if constexpr (EPI == 1) ((float*)outv)[idx] = v + res[idx];
        else if constexpr (EPI == 2) ((u16*)outv)[idx] = f2bf(gelu_f(v));
        else if constexpr (EPI == 3) ((float*)outv)[idx] = gelu_f(v) + res[idx];
        else if constexpr (EPI == 4) ((float*)outv)[idx] = v;
      }
    }
  }
}

// ---------------------------------------------------------------------------
// 128x128 single-buffered 16x16 GEMM — tiny head GEMMs (M=128), proven.
// EPI: 2=bf16 gelu(bias), 5=f32 gelu(bias) bounded store [Ms,Ns]
// ---------------------------------------------------------------------------
template<int EPI>
__global__ __launch_bounds__(256) void gemm_k(
    const u16* __restrict__ A, const u16* __restrict__ Bt,
    const float* __restrict__ bias, const float* __restrict__ res,
    void* __restrict__ outv, int K, int ldo, int nbn, int Ms, int Ns)
{
  __shared__ u16 As[128*64];
  __shared__ u16 Bs[128*64];
  const int tid = threadIdx.x;
  const int l   = tid & 63;
  const int w   = tid >> 6;
  const int wm  = w >> 1, wn = w & 1;
  const int lrow = l & 15;

  const int nwg = gridDim.x;
  const int q = nwg >> 3, r = nwg & 7;
  const int xcd = blockIdx.x & 7, o = blockIdx.x >> 3;
  const int wg = (xcd < r ? xcd * (q + 1) : r * (q + 1) + (xcd - r) * q) + o;
  const int bm = wg / nbn, bn = wg % nbn;

  const int cs8 = ((tid & 7) ^ ((tid >> 3) & 7)) * 8;
  const int rb  = tid >> 3;
  const size_t abase = (size_t)bm * 128 * K;
  const size_t bbase = (size_t)bn * 128 * K;
  size_t aoff[4], boff[4];
  #pragma unroll
  for (int i = 0; i < 4; i++) {
    aoff[i] = abase + (size_t)(rb + 32 * i) * K + cs8;
    boff[i] = bbase + (size_t)(rb + 32 * i) * K + cs8;
  }

  const int colA = (l >> 4) << 4;
  const int sw   = (lrow & 7) << 4;

  f32x4 acc[4][4];
  #pragma unroll
  for (int i = 0; i < 4; i++)
    #pragma unroll
    for (int j = 0; j < 4; j++) acc[i][j] = {0.f, 0.f, 0.f, 0.f};

  const int nk = K >> 6;
  for (int kt = 0; kt < nk; ++kt) {
    const int koff = kt * 64;
    #pragma unroll
    for (int i = 0; i < 4; i++) {
      gload16(A  + aoff[i] + koff, As + tid * 8 + i * 2048);
      gload16(Bt + boff[i] + koff, Bs + tid * 8 + i * 2048);
    }
    __syncthreads();
    #pragma unroll
    for (int kk = 0; kk < 2; kk++) {
      bf16x8 af[4], bfr[4];
      #pragma unroll
      for (int mi = 0; mi < 4; mi++)
        af[mi] = *(const bf16x8*)((const char*)As +
                  ((wm*64 + mi*16 + lrow) << 7) + (((kk << 6) | colA) ^ sw));
      #pragma unroll
      for (int ni = 0; ni < 4; ni++)
        bfr[ni] = *(const bf16x8*)((const char*)Bs +
                  ((wn*64 + ni*16 + lrow) << 7) + (((kk << 6) | colA) ^ sw));
      #pragma unroll
      for (int mi = 0; mi < 4; mi++)
        #pragma unroll
        for (int ni = 0; ni < 4; ni++)
          acc[mi][ni] = __builtin_amdgcn_mfma_f32_16x16x32_bf16(af[mi], bfr[ni], acc[mi][ni], 0, 0, 0);
    }
    __syncthreads();
  }

  const int orow0 = bm*128 + wm*64;
  const int ocol0 = bn*128 + wn*64;
  #pragma unroll
  for (int mi = 0; mi < 4; mi++) {
    #pragma unroll
    for (int ni = 0; ni < 4; ni++) {
      #pragma unroll
      for (int r2 = 0; r2 < 4; r2++) {
        const int row = orow0 + mi*16 + (l >> 4)*4 + r2;
        const int col = ocol0 + ni*16 + (l & 15);
        float bv;
        if constexpr (EPI == 5) bv = (col < Ns) ? bias[col] : 0.f;
        else bv = bias[col];
        const float v = acc[mi][ni][r2] + bv;
        const size_t idx = (size_t)row * ldo + col;
        if constexpr (EPI == 2) ((u16*)outv)[idx] = f2bf(gelu_f(v));
        else if constexpr (EPI == 5) {
          if (row < Ms && col < Ns) ((float*)outv)[(size_t)row * Ns + col] = gelu_f(v);
        }
      }
    }
  }
}

// ---------------------------------------------------------------------------
__global__ void wconv_k(const float* __restrict__ W, u16* __restrict__ Wt,
                        int K, int N)
{
  __shared__ float tile[32][33];
  const int n0 = blockIdx.x * 32, k0 = blockIdx.y * 32;
  const int tx = threadIdx.x, ty = threadIdx.y;
  #pragma unroll
  for (int r = 0; r < 4; r++) {
    const int kk = k0 + ty + r*8;
    const int nn = n0 + tx;
    tile[ty + r*8][tx] = (nn < N) ? W[(size_t)kk * N + nn] : 0.f;
  }
  __syncthreads();
  #pragma unroll
  for (int r = 0; r < 4; r++) {
    const int nn = n0 + ty + r*8;
    Wt[(size_t)nn * K + k0 + tx] = f2bf(tile[tx][ty + r*8]);
  }
}

// ---------------------------------------------------------------------------
__global__ void patchify_k(const float* __restrict__ x, u16* __restrict__ hb)
{
  const int blk = blockIdx.x;
  const int b = blk / NP_, p = blk % NP_;
  const int pr = p / 24, pc = p % 24;
  const size_t row = (size_t)b * NT_ + 1 + p;
  #pragma unroll
  for (int u = 0; u < 3; u++) {
    const int j  = threadIdx.x + u * 256;
    const int c  = j >> 8, ph = (j >> 4) & 15, pw = j & 15;
    const float v = x[((size_t)(b*3 + c) * IMG_ + pr*16 + ph) * IMG_ + pc*16 + pw];
    hb[row * D_ + j] = f2bf(v);
  }
}

__global__ void posecls_k(float* __restrict__ z, const float* __restrict__ ce,
                          const float* __restrict__ pe)
{
  const int row = blockIdx.x;
  const int t = row % NT_;
  const size_t base = (size_t)row * D_;
  #pragma unroll
  for (int u = 0; u < 3; u++) {
    const int j = threadIdx.x + u * 256;
    if (t == 0) z[base + j] = ce[j] + pe[j];
    else        z[base + j] += pe[(size_t)t * D_ + j];
  }
}

// LayerNorm: one wave per row, float4 loads, f32 in -> bf16 out
__global__ void ln_k(const float* __restrict__ z, const float* __restrict__ w,
                     const float* __restrict__ b, u16* __restrict__ out)
{
  const int row = blockIdx.x * 4 + (threadIdx.x >> 6);
  const int l = threadIdx.x & 63;
  const float4* zr = (const float4*)(z + (size_t)row * D_);
  float4 xq[3];
  float s = 0.f;
  #pragma unroll
  for (int j = 0; j < 3; j++) {
    xq[j] = zr[j*64 + l];
    s += xq[j].x + xq[j].y + xq[j].z + xq[j].w;
  }
  #pragma unroll
  for (int m = 1; m < 64; m <<= 1) s += __shfl_xor(s, m, 64);
  const float mean = s * (1.0f / 768.0f);
  float ss = 0.f;
  #pragma unroll
  for (int j = 0; j < 3; j++) {
    const float dx = xq[j].x-mean, dy = xq[j].y-mean, dz = xq[j].z-mean, dw = xq[j].w-mean;
    ss += dx*dx + dy*dy + dz*dz + dw*dw;
  }
  #pragma unroll
  for (int m = 1; m < 64; m <<= 1) ss += __shfl_xor(ss, m, 64);
  const float rinv = rsqrtf(ss * (1.0f / 768.0f) + 1e-5f);
  const size_t ob = (size_t)row * D_;
  #pragma unroll
  for (int j = 0; j < 3; j++) {
    const int c = (j*64 + l) * 4;
    const float4 wv = *(const float4*)(w + c);
    const float4 bv = *(const float4*)(b + c);
    ushort4 ov;
    ov.x = f2bf((xq[j].x - mean) * rinv * wv.x + bv.x);
    ov.y = f2bf((xq[j].y - mean) * rinv * wv.y + bv.y);
    ov.z = f2bf((xq[j].z - mean) * rinv * wv.z + bv.z);
    ov.w = f2bf((xq[j].w - mean) * rinv * wv.w + bv.w);
    *(ushort4*)(out + ob + c) = ov;
  }
}

// Final LN over cls rows -> yb[128][768] bf16 (rows >= 64 zeroed)
__global__ void lncls_k(const float* __restrict__ z, const float* __restrict__ w,
                        const float* __restrict__ b, u16* __restrict__ out)
{
  const int row = blockIdx.x * 4 + (threadIdx.x >> 6);   // 0..127
  const int l = threadIdx.x & 63;
  const size_t ob = (size_t)row * D_;
  if (row >= B_) {
    #pragma unroll
    for (int j = 0; j < 12; j++) out[ob + j*64 + l] = 0;
    return;
  }
  const float* zr = z + (size_t)row * NT_ * D_;
  float xv[12];
  float s = 0.f;
  #pragma unroll
  for (int j = 0; j < 12; j++) { xv[j] = zr[j*64 + l]; s += xv[j]; }
  #pragma unroll
  for (int m = 1; m < 64; m <<= 1) s += __shfl_xor(s, m, 64);
  const float mean = s * (1.0f / 768.0f);
  float ss = 0.f;
  #pragma unroll
  for (int j = 0; j < 12; j++) { const float d = xv[j] - mean; ss += d * d; }
  #pragma unroll
  for (int m = 1; m < 64; m <<= 1) ss += __shfl_xor(ss, m, 64);
  const float rinv = rsqrtf(ss * (1.0f / 768.0f) + 1e-5f);
  #pragma unroll
  for (int j = 0; j < 12; j++) {
    const int cidx = j*64 + l;
    out[ob + cidx] = f2bf((xv[j] - mean) * rinv * w[cidx] + b[cidx]);
  }
}

// ---------------------------------------------------------------------------
// MFMA per-token head-axis attention (round-3 proven).
// ---------------------------------------------------------------------------
__global__ __launch_bounds__(256) void attn_k(const u16* __restrict__ qkv,
                                              u16* __restrict__ o)
{
  const int tok = (blockIdx.x * 256 + threadIdx.x) >> 6;
  const int l  = threadIdx.x & 63;
  const int g  = l >> 4, li = l & 15;
  const size_t rb = (size_t)tok * (3 * D_);

  f32x4 s = {0.f, 0.f, 0.f, 0.f};
  #pragma unroll
  for (int kt = 0; kt < 2; kt++) {
    const bf16x8 ka = *(const bf16x8*)(qkv + rb + D_ + li*64 + g*8 + kt*32);
    const bf16x8 qb = *(const bf16x8*)(qkv + rb +      li*64 + g*8 + kt*32);
    s = __builtin_amdgcn_mfma_f32_16x16x32_bf16(ka, qb, s, 0, 0, 0);
  }

  float sv[4];
  #pragma unroll
  for (int r2 = 0; r2 < 4; r2++) sv[r2] = s[r2] * 0.125f;
  float mx = (g < 3) ? fmaxf(fmaxf(sv[0], sv[1]), fmaxf(sv[2], sv[3])) : -1e30f;
  mx = fmaxf(mx, __shfl_xor(mx, 16, 64));
  mx = fmaxf(mx, __shfl_xor(mx, 32, 64));
  float p[4], den = 0.f;
  #pragma unroll
  for (int r2 = 0; r2 < 4; r2++) {
    p[r2] = (g < 3) ? __expf(sv[r2] - mx) : 0.f;
    den += p[r2];
  }
  den += __shfl_xor(den, 16, 64);
  den += __shfl_xor(den, 32, 64);
  const float rden = 1.0f / den;
  #pragma unroll
  for (int r2 = 0; r2 < 4; r2++) p[r2] *= rden;

  const u32 pk01 = ((u32)f2bf(p[1]) << 16) | f2bf(p[0]);
  const u32 pk23 = ((u32)f2bf(p[3]) << 16) | f2bf(p[2]);

  const int srcA = (li + (g << 5)) & 63;
  const int srcB = (srcA + 16) & 63;
  u32 b0 = (u32)__shfl((int)pk01, srcA, 64);
  u32 b1 = (u32)__shfl((int)pk23, srcA, 64);
  u32 b2 = (u32)__shfl((int)pk01, srcB, 64);
  u32 b3 = (u32)__shfl((int)pk23, srcB, 64);
  if (g >= 2) { b0 = 0; b1 = 0; b2 = 0; b3 = 0; }
  union { u32 u[4]; bf16x8 v; } pb;
  pb.u[0] = b0; pb.u[1] = b1; pb.u[2] = b2; pb.u[3] = b3;

  const size_t ob = (size_t)tok * D_;
  #pragma unroll
  for (int t = 0; t < 4; t++) {
    union { u16 a[8]; bf16x8 v; } va;
    #pragma unroll
    for (int jp = 0; jp < 8; jp++) {
      const int j = g * 8 + jp;
      va.a[jp] = (j < 12) ? qkv[rb + 2*D_ + j*64 + t*16 + li] : (u16)0;
    }
    f32x4 oac = {0.f, 0.f, 0.f, 0.f};
    oac = __builtin_amdgcn_mfma_f32_16x16x32_bf16(va.v, pb.v, oac, 0, 0, 0);
    if (li < 12) {
      ushort4 ov;
      ov.x = f2bf(oac[0]); ov.y = f2bf(oac[1]);
      ov.z = f2bf(oac[2]); ov.w = f2bf(oac[3]);
      *(ushort4*)(o + ob + li*64 + t*16 + g*4) = ov;
    }
  }
}

// ---------------------------------------------------------------------------
extern "C" void kernel_launch(void* const* d_in, const int* in_sizes, int n_in,
                              void* d_out, int out_size, void* d_ws, size_t ws_size,
                              hipStream_t stream)
{
  const float* x    = (const float*)d_in[0];
  const float* ce   = (const float*)d_in[1];
  const float* pe   = (const float*)d_in[2];
  const float* pw   = (const float*)d_in[3];
  const float* pb   = (const float*)d_in[4];
  const float* qkvw = (const float*)d_in[5];
  const float* qkvb = (const float*)d_in[6];
  const float* topw = (const float*)d_in[7];
  const float* topb = (const float*)d_in[8];
  const float* l1w  = (const float*)d_in[9];
  const float* l1b  = (const float*)d_in[10];
  const float* l2w  = (const float*)d_in[11];
  const float* l2b  = (const float*)d_in[12];
  const float* w1   = (const float*)d_in[13];
  const float* b1   = (const float*)d_in[14];
  const float* w2   = (const float*)d_in[15];
  const float* b2   = (const float*)d_in[16];
  const float* l3w  = (const float*)d_in[17];
  const float* l3b  = (const float*)d_in[18];
  const float* hw1  = (const float*)d_in[19];
  const float* hb1  = (const float*)d_in[20];
  const float* hw2  = (const float*)d_in[21];
  const float* hb2  = (const float*)d_in[22];

  char* ws = (char*)d_ws;
  constexpr size_t SZ_Z  = (size_t)MPAD2 * D_ * 4;
  constexpr size_t SZ_HB = (size_t)MPAD2 * D_ * 2;
  constexpr size_t SZ_QM = (size_t)MPAD2 * DM_ * 2;
  constexpr size_t SZ_WB = (size_t)DM_ * 1024 * 2;
  constexpr size_t SZ_YB = (size_t)128 * D_ * 2;
  float* z  = (float*)ws;
  u16*   hb = (u16*)(ws + SZ_Z);
  u16*   qm = (u16*)(ws + SZ_Z + SZ_HB);
  u16*   wb = (u16*)(ws + SZ_Z + SZ_HB + SZ_QM);
  u16*   yb = (u16*)(ws + SZ_Z + SZ_HB + SZ_QM + SZ_WB);
  u16*   t1 = (u16*)(ws + SZ_Z + SZ_HB + SZ_QM + SZ_WB + SZ_YB);

  const dim3 blk(256);
  const dim3 blk5(512);
  const dim3 wblk(32, 8);
  const int MT2 = MPAD2 / 256;  // 145

  // Patch embedding
  patchify_k<<<B_ * NP_, blk, 0, stream>>>(x, hb);
  wconv_k<<<dim3(D_/32, D_/32), wblk, 0, stream>>>(pw, wb, D_, D_);
  gemm256_k<4><<<3*MT2, blk5, 0, stream>>>(hb, wb, pb, nullptr, z, D_, D_, 3);
  posecls_k<<<MREAL, blk, 0, stream>>>(z, ce, pe);

  for (int i = 0; i < NL_; i++) {
    ln_k<<<MPAD2/4, blk, 0, stream>>>(z, l1w + i*D_, l1b + i*D_, hb);
    wconv_k<<<dim3(3*D_/32, D_/32), wblk, 0, stream>>>(qkvw + (size_t)i*D_*3*D_, wb, D_, 3*D_);
    gemm256_k<0><<<9*MT2, blk5, 0, stream>>>(hb, wb, qkvb + i*3*D_, nullptr, qm, D_, 3*D_, 9);
    attn_k<<<MREAL/4, blk, 0, stream>>>(qm, hb);
    wconv_k<<<dim3(D_/32, D_/32), wblk, 0, stream>>>(topw + (size_t)i*D_*D_, wb, D_, D_);
    gemm256_k<1><<<3*MT2, blk5, 0, stream>>>(hb, wb, topb + i*D_, z, z, D_, D_, 3);
    ln_k<<<MPAD2/4, blk, 0, stream>>>(z, l2w + i*D_, l2b + i*D_, hb);
    wconv_k<<<dim3(DM_/32, D_/32), wblk, 0, stream>>>(w1 + (size_t)i*D_*DM_, wb, D_, DM_);
    gemm256_k<2><<<12*MT2, blk5, 0, stream>>>(hb, wb, b1 + i*DM_, nullptr, qm, D_, DM_, 12);
    wconv_k<<<dim3(D_/32, DM_/32), wblk, 0, stream>>>(w2 + (size_t)i*DM_*D_, wb, DM_, D_);
    gemm256_k<3><<<3*MT2, blk5, 0, stream>>>(qm, wb, b2 + i*D_, z, z, DM_, D_, 3);
  }

  // Head: LN(cls) -> MLP with gelu after both linears (small M -> old kernel)
  lncls_k<<<32, blk, 0, stream>>>(z, l3w, l3b, yb);
  wconv_k<<<dim3(DM_/32, D_/32), wblk, 0, stream>>>(hw1, wb, D_, DM_);
  gemm_k<2><<<24, blk, 0, stream>>>(yb, wb, hb1, nullptr, t1, D_, DM_, 24, 0, 0);
  wconv_k<<<dim3(1024/32, DM_/32), wblk, 0, stream>>>(hw2, wb, DM_, NC_);
  gemm_k<5><<<8, blk, 0, stream>>>(t1, wb, hb2, nullptr, (float*)d_out, DM_, 1024, 8, B_, NC_);
}

// Round 12
// 11327.086 us; speedup vs baseline: 1.3102x; 1.0562x over previous
//
#include <hip/hip_runtime.h>

typedef unsigned short u16;
typedef unsigned int u32;
typedef __bf16 bf16x8 __attribute__((ext_vector_type(8)));
typedef float f32x4 __attribute__((ext_vector_type(4)));

#define D_    768
#define DM_   3072
#define NL_   12
#define NT_   577
#define NP_   576
#define B_    64
#define MREAL (B_*NT_)      /* 36928 */
#define MPAD2 37120         /* 145*256 = 290*128 */
#define NC_   1000
#define IMG_  384

__device__ __forceinline__ float bf2f(u16 v){
  union { unsigned u; float f; } c; c.u = ((unsigned)v) << 16; return c.f;
}
__device__ __forceinline__ u16 f2bf(float f){
  union { float f; unsigned u; } c; c.f = f;
  unsigned r = c.u + 0x7FFFu + ((c.u >> 16) & 1u);
  return (u16)(r >> 16);
}
__device__ __forceinline__ float gelu_f(float x){
  return 0.5f * x * (1.0f + erff(x * 0.70710678118654752f));
}
__device__ __forceinline__ void gload16(const void* g, void* l){
  __builtin_amdgcn_global_load_lds((const __attribute__((address_space(1))) void*)g,
                                   (__attribute__((address_space(3))) void*)l, 16, 0, 0);
}
#define SB_ __builtin_amdgcn_sched_barrier(0)

// ---------------------------------------------------------------------------
// Deep-prefetch ring GEMM (qkv/mlp1): 128x128 tile, BK=32, 4 waves (2x2),
// 3-slot LDS ring (48 KiB -> 3 blocks/CU). Tile t staged at iter t-2: 2-iter
// latency cover + 3 de-phased blocks/CU. Counted vmcnt(8) (12 outstanding,
// retire oldest 4); tail peeled vmcnt(4)/vmcnt(0).
// Packed-row LDS layout (round-8 verified, 2-way bank alias only):
//   byte = (row>>1)*128 + (row&1)*64 + ((slot ^ ((row>>1)&3))<<4)
// staged via linear dest + inverse-permuted per-lane SOURCE (rule 21).
// EPI: 0=bf16 bias, 2=bf16 gelu(bias)
// ---------------------------------------------------------------------------
template<int EPI>
__global__ __launch_bounds__(256, 3) void gemmR_k(
    const u16* __restrict__ A, const u16* __restrict__ Bt,
    const float* __restrict__ bias,
    void* __restrict__ outv, int K, int ldo, int nbn)
{
  __shared__ u16 ring[3][2][4096];   // [slot][A|B][8KB] = 48 KiB
  const int tid = threadIdx.x;
  const int l   = tid & 63;
  const int w   = tid >> 6;
  const int wm  = w >> 1, wn = w & 1;
  const int lrow = l & 15;
  const int g2   = l >> 4;           // 0..3 k-slot

  // bijective XCD swizzle (m204), bn-fastest
  const int nwg = gridDim.x;
  const int q = nwg >> 3, r = nwg & 7;
  const int xcd = blockIdx.x & 7, o = blockIdx.x >> 3;
  const int wg = (xcd < r ? xcd * (q + 1) : r * (q + 1) + (xcd - r) * q) + o;
  const int bm = wg / nbn, bn = wg % nbn;

  // staging source: dest byte = tid*16 + i*4096 decodes to
  // rowpair rp = (tid>>3)+32*i, rodd = (tid>>2)&1, se = tid&3;
  // source col slot = se ^ (rp&3)  (rp&3 independent of i since 32%4==0)
  const int rp0  = tid >> 3;
  const int rodd = (tid >> 2) & 1;
  const int scol = ((tid & 3) ^ (rp0 & 3)) * 8;   // elements
  const u16* aS[2]; const u16* bS[2];
  #pragma unroll
  for (int i = 0; i < 2; i++) {
    const int row = (rp0 + 32*i) * 2 + rodd;
    aS[i] = A  + (size_t)(bm*128 + row) * K + scol;
    bS[i] = Bt + (size_t)(bn*128 + row) * K + scol;
  }
  const int dst = tid * 8;   // u16 units (16B per thread)

  // fragment read byte offsets within an 8KB tile region
  int afo[4], bfo[4];
  #pragma unroll
  for (int mi = 0; mi < 4; mi++) {
    const int ar = wm*64 + mi*16 + lrow;
    afo[mi] = (ar >> 1)*128 + (ar & 1)*64 + ((g2 ^ ((ar >> 1) & 3)) << 4);
    const int br = wn*64 + mi*16 + lrow;
    bfo[mi] = (br >> 1)*128 + (br & 1)*64 + ((g2 ^ ((br >> 1) & 3)) << 4);
  }

  f32x4 acc[4][4];
  #pragma unroll
  for (int i = 0; i < 4; i++)
    #pragma unroll
    for (int j = 0; j < 4; j++) acc[i][j] = {0.f, 0.f, 0.f, 0.f};

  const int nt = K >> 5;   // BK=32 tiles (24 for K=768)

#define STG_R(t_) { \
    const int sl_ = (t_) % 3; const int ko_ = (t_) * 32; \
    gload16(aS[0] + ko_, &ring[sl_][0][dst]); \
    gload16(aS[1] + ko_, &ring[sl_][0][dst + 2048]); \
    gload16(bS[0] + ko_, &ring[sl_][1][dst]); \
    gload16(bS[1] + ko_, &ring[sl_][1][dst + 2048]); }

#define CMP_R(t_) { \
    const int sl_ = (t_) % 3; \
    const char* As_ = (const char*)&ring[sl_][0][0]; \
    const char* Bs_ = (const char*)&ring[sl_][1][0]; \
    bf16x8 af[4], bfr[4]; \
    _Pragma("unroll") \
    for (int mi = 0; mi < 4; mi++) af[mi]  = *(const bf16x8*)(As_ + afo[mi]); \
    _Pragma("unroll") \
    for (int ni = 0; ni < 4; ni++) bfr[ni] = *(const bf16x8*)(Bs_ + bfo[ni]); \
    asm volatile("s_waitcnt lgkmcnt(0)" ::: "memory"); \
    SB_; \
    __builtin_amdgcn_s_setprio(1); \
    _Pragma("unroll") \
    for (int mi = 0; mi < 4; mi++) \
      _Pragma("unroll") \
      for (int ni = 0; ni < 4; ni++) \
        acc[mi][ni] = __builtin_amdgcn_mfma_f32_16x16x32_bf16(af[mi], bfr[ni], acc[mi][ni], 0, 0, 0); \
    __builtin_amdgcn_s_setprio(0); \
    SB_; \
    __builtin_amdgcn_s_barrier(); \
    SB_; }

  // prologue: stage tiles 0,1
  STG_R(0); STG_R(1);

  for (int t = 0; t < nt - 2; ++t) {
    STG_R(t + 2);
    SB_;
    asm volatile("s_waitcnt vmcnt(8)" ::: "memory");
    SB_;
    __builtin_amdgcn_s_barrier();
    SB_;
    CMP_R(t);
  }
  // tail t = nt-2
  SB_; asm volatile("s_waitcnt vmcnt(4)" ::: "memory"); SB_;
  __builtin_amdgcn_s_barrier(); SB_;
  CMP_R(nt - 2);
  // tail t = nt-1
  SB_; asm volatile("s_waitcnt vmcnt(0)" ::: "memory"); SB_;
  __builtin_amdgcn_s_barrier(); SB_;
  CMP_R(nt - 1);

#undef STG_R
#undef CMP_R

  const int orow0 = bm*128 + wm*64;
  const int ocol0 = bn*128 + wn*64;
  #pragma unroll
  for (int mi = 0; mi < 4; mi++) {
    #pragma unroll
    for (int ni = 0; ni < 4; ni++) {
      const int col = ocol0 + ni*16 + lrow;
      const float bv = bias[col];
      #pragma unroll
      for (int r2 = 0; r2 < 4; r2++) {
        const int row = orow0 + mi*16 + g2*4 + r2;
        const float v = acc[mi][ni][r2] + bv;
        const size_t idx = (size_t)row * ldo + col;
        if constexpr (EPI == 0) ((u16*)outv)[idx] = f2bf(v);
        else if constexpr (EPI == 2) ((u16*)outv)[idx] = f2bf(gelu_f(v));
      }
    }
  }
}

// ---------------------------------------------------------------------------
// 256x256 GEMM, 4-phase split, 16x16x32 (round-5 proven) — pe/top/mlp2.
// EPI: 1=f32 bias+res, 3=f32 gelu(bias)+res, 4=f32 bias
// ---------------------------------------------------------------------------
template<int EPI>
__global__ __launch_bounds__(512, 1) void gemm256_k(
    const u16* __restrict__ A, const u16* __restrict__ Bt,
    const float* __restrict__ bias, const float* __restrict__ res,
    void* __restrict__ outv, int K, int ldo, int nbn)
{
  __shared__ u16 lds[2][2][256*64];
  const int tid = threadIdx.x;
  const int l   = tid & 63;
  const int wid = tid >> 6;
  const int wm  = wid >> 2, wn = wid & 3;
  const int lrow = l & 15;

  const int nwg = gridDim.x;
  const int q = nwg >> 3, r = nwg & 7;
  const int xcd = blockIdx.x & 7, o = blockIdx.x >> 3;
  const int wg = (xcd < r ? xcd * (q + 1) : r * (q + 1) + (xcd - r) * q) + o;
  const int bm = wg / nbn, bn = wg % nbn;

  const int cs8 = ((tid & 7) ^ ((tid >> 3) & 7)) * 8;
  const int rb  = tid >> 3;
  const u16* aP[4]; const u16* bP[4];
  #pragma unroll
  for (int i = 0; i < 4; i++) {
    aP[i] = A  + (size_t)(bm*256 + rb + 64*i) * K + cs8;
    bP[i] = Bt + (size_t)(bn*256 + rb + 64*i) * K + cs8;
  }
  const int ldst = tid * 8;

  f32x4 acc[8][4];
  #pragma unroll
  for (int i = 0; i < 8; i++)
    #pragma unroll
    for (int j = 0; j < 4; j++) acc[i][j] = {0.f, 0.f, 0.f, 0.f};

  const int nk = K >> 6;
  #pragma unroll
  for (int i = 0; i < 4; i++) {
    gload16(aP[i], &lds[0][0][ldst + i*4096]);
    gload16(bP[i], &lds[0][1][ldst + i*4096]);
    aP[i] += 64; bP[i] += 64;
  }

  const int sw  = (lrow & 7) << 4;
  const int g16 = (l >> 4) << 4;

  for (int t = 0; t < nk; ++t) {
    const int cur = t & 1;
    const bool pre = (t + 1 < nk);
    u16* dA = &lds[cur^1][0][0];
    u16* dB = &lds[cur^1][1][0];

    if (pre) {
      gload16(aP[0], dA + ldst);
      gload16(aP[1], dA + ldst + 4096);
    }
    SB_;
    if (pre) asm volatile("s_waitcnt vmcnt(2)" ::: "memory");
    else     asm volatile("s_waitcnt vmcnt(0)" ::: "memory");
    SB_;
    __builtin_amdgcn_s_barrier();
    SB_;

    const char* As_ = (const char*)&lds[cur][0][0];
    const char* Bs_ = (const char*)&lds[cur][1][0];
    bf16x8 af[4], bfr[4];

    {
      const int kb = g16;
      #pragma unroll
      for (int ni = 0; ni < 4; ni++)
        bfr[ni] = *(const bf16x8*)(Bs_ + ((wn*64 + ni*16 + lrow) << 7) + (kb ^ sw));
      #pragma unroll
      for (int mi = 0; mi < 4; mi++)
        af[mi] = *(const bf16x8*)(As_ + ((wm*128 + mi*16 + lrow) << 7) + (kb ^ sw));
      if (pre) {
        gload16(aP[2], dA + ldst + 8192);
        gload16(aP[3], dA + ldst + 12288);
      }
      asm volatile("s_waitcnt lgkmcnt(0)" ::: "memory");
      SB_;
      __builtin_amdgcn_s_setprio(1);
      #pragma unroll
      for (int mi = 0; mi < 4; mi++)
        #pragma unroll
        for (int ni = 0; ni < 4; ni++)
          acc[mi][ni] = __builtin_amdgcn_mfma_f32_16x16x32_bf16(af[mi], bfr[ni], acc[mi][ni], 0, 0, 0);
      __builtin_amdgcn_s_setprio(0);
      SB_;
      __builtin_amdgcn_s_barrier();
      SB_;
    }
    {
      const int kb = g16;
      #pragma unroll
      for (int mi = 0; mi < 4; mi++)
        af[mi] = *(const bf16x8*)(As_ + ((wm*128 + (mi+4)*16 + lrow) << 7) + (kb ^ sw));
      if (pre) {
        gload16(bP[0], dB + ldst);
        gload16(bP[1], dB + ldst + 4096);
      }
      asm volatile("s_waitcnt lgkmcnt(0)" ::: "memory");
      SB_;
      __builtin_amdgcn_s_setprio(1);
      #pragma unroll
      for (int mi = 0; mi < 4; mi++)
        #pragma unroll
        for (int ni = 0; ni < 4; ni++)
          acc[mi+4][ni] = __builtin_amdgcn_mfma_f32_16x16x32_bf16(af[mi], bfr[ni], acc[mi+4][ni], 0, 0, 0);
      __builtin_amdgcn_s_setprio(0);
      SB_;
      __builtin_amdgcn_s_barrier();
      SB_;
    }
    {
      const int kb = 64 | g16;
      #pragma unroll
      for (int ni = 0; ni < 4; ni++)
        bfr[ni] = *(const bf16x8*)(Bs_ + ((wn*64 + ni*16 + lrow) << 7) + (kb ^ sw));
      #pragma unroll
      for (int mi = 0; mi < 4; mi++)
        af[mi] = *(const bf16x8*)(As_ + ((wm*128 + mi*16 + lrow) << 7) + (kb ^ sw));
      if (pre) {
        gload16(bP[2], dB + ldst + 8192);
        gload16(bP[3], dB + ldst + 12288);
      }
      asm volatile("s_waitcnt lgkmcnt(0)" ::: "memory");
      SB_;
      __builtin_amdgcn_s_setprio(1);
      #pragma unroll
      for (int mi = 0; mi < 4; mi++)
        #pragma unroll
        for (int ni = 0; ni < 4; ni++)
          acc[mi][ni] = __builtin_amdgcn_mfma_f32_16x16x32_bf16(af[mi], bfr[ni], acc[mi][ni], 0, 0, 0);
      __builtin_amdgcn_s_setprio(0);
      SB_;
      __builtin_amdgcn_s_barrier();
      SB_;
    }
    {
      const int kb = 64 | g16;
      #pragma unroll
      for (int mi = 0; mi < 4; mi++)
        af[mi] = *(const bf16x8*)(As_ + ((wm*128 + (mi+4)*16 + lrow) << 7) + (kb ^ sw));
      asm volatile("s_waitcnt lgkmcnt(0)" ::: "memory");
      SB_;
      __builtin_amdgcn_s_setprio(1);
      #pragma unroll
      for (int mi = 0; mi < 4; mi++)
        #pragma unroll
        for (int ni = 0; ni < 4; ni++)
          acc[mi+4][ni] = __builtin_amdgcn_mfma_f32_16x16x32_bf16(af[mi], bfr[ni], acc[mi+4][ni], 0, 0, 0);
      __builtin_amdgcn_s_setprio(0);
      SB_;
      __builtin_amdgcn_s_barrier();
      SB_;
    }
    if (pre) {
      #pragma unroll
      for (int i = 0; i < 4; i++) { aP[i] += 64; bP[i] += 64; }
    }
  }

  const int orow0 = bm*256 + wm*128;
  const int ocol0 = bn*256 + wn*64;
  #pragma unroll
  for (int mi = 0; mi < 8; mi++) {
    #pragma unroll
    for (int ni = 0; ni < 4; ni++) {
      const int col = ocol0 + ni*16 + (l & 15);
      const float bv = bias[col];
      #pragma unroll
      for (int r2 = 0; r2 < 4; r2++) {
        const int row = orow0 + mi*16 + (l >> 4)*4 + r2;
        const float v = acc[mi][ni][r2] + bv;
        const size_t idx = (size_t)row * ldo + col;
        if constexpr (EPI == 1) ((float*)outv)[idx] = v + res[idx];
        else if constexpr (EPI == 3) ((float*)outv)[idx] = gelu_f(v) + res[idx];
        else if constexpr (EPI == 4) ((float*)outv)[idx] = v;
      }
    }
  }
}

// ---------------------------------------------------------------------------
// 128x128 single-buffered GEMM — tiny head GEMMs (M=128).
// EPI: 2=bf16 gelu(bias), 5=f32 gelu(bias) bounded store [Ms,Ns]
// ---------------------------------------------------------------------------
template<int EPI>
__global__ __launch_bounds__(256) void gemm_k(
    const u16* __restrict__ A, const u16* __restrict__ Bt,
    const float* __restrict__ bias, const float* __restrict__ res,
    void* __restrict__ outv, int K, int ldo, int nbn, int Ms, int Ns)
{
  __shared__ u16 As[128*64];
  __shared__ u16 Bs[128*64];
  const int tid = threadIdx.x;
  const int l   = tid & 63;
  const int w   = tid >> 6;
  const int wm  = w >> 1, wn = w & 1;
  const int lrow = l & 15;

  const int nwg = gridDim.x;
  const int q = nwg >> 3, r = nwg & 7;
  const int xcd = blockIdx.x & 7, o = blockIdx.x >> 3;
  const int wg = (xcd < r ? xcd * (q + 1) : r * (q + 1) + (xcd - r) * q) + o;
  const int bm = wg / nbn, bn = wg % nbn;

  const int cs8 = ((tid & 7) ^ ((tid >> 3) & 7)) * 8;
  const int rb  = tid >> 3;
  const size_t abase = (size_t)bm * 128 * K;
  const size_t bbase = (size_t)bn * 128 * K;
  size_t aoff[4], boff[4];
  #pragma unroll
  for (int i = 0; i < 4; i++) {
    aoff[i] = abase + (size_t)(rb + 32 * i) * K + cs8;
    boff[i] = bbase + (size_t)(rb + 32 * i) * K + cs8;
  }

  const int colA = (l >> 4) << 4;
  const int sw   = (lrow & 7) << 4;

  f32x4 acc[4][4];
  #pragma unroll
  for (int i = 0; i < 4; i++)
    #pragma unroll
    for (int j = 0; j < 4; j++) acc[i][j] = {0.f, 0.f, 0.f, 0.f};

  const int nk = K >> 6;
  for (int kt = 0; kt < nk; ++kt) {
    const int koff = kt * 64;
    #pragma unroll
    for (int i = 0; i < 4; i++) {
      gload16(A  + aoff[i] + koff, As + tid * 8 + i * 2048);
      gload16(Bt + boff[i] + koff, Bs + tid * 8 + i * 2048);
    }
    __syncthreads();
    #pragma unroll
    for (int kk = 0; kk < 2; kk++) {
      bf16x8 af[4], bfr[4];
      #pragma unroll
      for (int mi = 0; mi < 4; mi++)
        af[mi] = *(const bf16x8*)((const char*)As +
                  ((wm*64 + mi*16 + lrow) << 7) + (((kk << 6) | colA) ^ sw));
      #pragma unroll
      for (int ni = 0; ni < 4; ni++)
        bfr[ni] = *(const bf16x8*)((const char*)Bs +
                  ((wn*64 + ni*16 + lrow) << 7) + (((kk << 6) | colA) ^ sw));
      #pragma unroll
      for (int mi = 0; mi < 4; mi++)
        #pragma unroll
        for (int ni = 0; ni < 4; ni++)
          acc[mi][ni] = __builtin_amdgcn_mfma_f32_16x16x32_bf16(af[mi], bfr[ni], acc[mi][ni], 0, 0, 0);
    }
    __syncthreads();
  }

  const int orow0 = bm*128 + wm*64;
  const int ocol0 = bn*128 + wn*64;
  #pragma unroll
  for (int mi = 0; mi < 4; mi++) {
    #pragma unroll
    for (int ni = 0; ni < 4; ni++) {
      #pragma unroll
      for (int r2 = 0; r2 < 4; r2++) {
        const int row = orow0 + mi*16 + (l >> 4)*4 + r2;
        const int col = ocol0 + ni*16 + (l & 15);
        float bv;
        if constexpr (EPI == 5) bv = (col < Ns) ? bias[col] : 0.f;
        else bv = bias[col];
        const float v = acc[mi][ni][r2] + bv;
        const size_t idx = (size_t)row * ldo + col;
        if constexpr (EPI == 2) ((u16*)outv)[idx] = f2bf(gelu_f(v));
        else if constexpr (EPI == 5) {
          if (row < Ms && col < Ns) ((float*)outv)[(size_t)row * Ns + col] = gelu_f(v);
        }
      }
    }
  }
}

// ---------------------------------------------------------------------------
__global__ void wconv_k(const float* __restrict__ W, u16* __restrict__ Wt,
                        int K, int N)
{
  __shared__ float tile[32][33];
  const int n0 = blockIdx.x * 32, k0 = blockIdx.y * 32;
  const int tx = threadIdx.x, ty = threadIdx.y;
  #pragma unroll
  for (int r = 0; r < 4; r++) {
    const int kk = k0 + ty + r*8;
    const int nn = n0 + tx;
    tile[ty + r*8][tx] = (nn < N) ? W[(size_t)kk * N + nn] : 0.f;
  }
  __syncthreads();
  #pragma unroll
  for (int r = 0; r < 4; r++) {
    const int nn = n0 + ty + r*8;
    Wt[(size_t)nn * K + k0 + tx] = f2bf(tile[tx][ty + r*8]);
  }
}

// ---------------------------------------------------------------------------
__global__ void patchify_k(const float* __restrict__ x, u16* __restrict__ hb)
{
  const int blk = blockIdx.x;
  const int b = blk / NP_, p = blk % NP_;
  const int pr = p / 24, pc = p % 24;
  const size_t row = (size_t)b * NT_ + 1 + p;
  #pragma unroll
  for (int u = 0; u < 3; u++) {
    const int j  = threadIdx.x + u * 256;
    const int c  = j >> 8, ph = (j >> 4) & 15, pw = j & 15;
    const float v = x[((size_t)(b*3 + c) * IMG_ + pr*16 + ph) * IMG_ + pc*16 + pw];
    hb[row * D_ + j] = f2bf(v);
  }
}

__global__ void posecls_k(float* __restrict__ z, const float* __restrict__ ce,
                          const float* __restrict__ pe)
{
  const int row = blockIdx.x;
  const int t = row % NT_;
  const size_t base = (size_t)row * D_;
  #pragma unroll
  for (int u = 0; u < 3; u++) {
    const int j = threadIdx.x + u * 256;
    if (t == 0) z[base + j] = ce[j] + pe[j];
    else        z[base + j] += pe[(size_t)t * D_ + j];
  }
}

// LayerNorm: one wave per row, float4 loads, f32 in -> bf16 out
__global__ void ln_k(const float* __restrict__ z, const float* __restrict__ w,
                     const float* __restrict__ b, u16* __restrict__ out)
{
  const int row = blockIdx.x * 4 + (threadIdx.x >> 6);
  const int l = threadIdx.x & 63;
  const float4* zr = (const float4*)(z + (size_t)row * D_);
  float4 xq[3];
  float s = 0.f;
  #pragma unroll
  for (int j = 0; j < 3; j++) {
    xq[j] = zr[j*64 + l];
    s += xq[j].x + xq[j].y + xq[j].z + xq[j].w;
  }
  #pragma unroll
  for (int m = 1; m < 64; m <<= 1) s += __shfl_xor(s, m, 64);
  const float mean = s * (1.0f / 768.0f);
  float ss = 0.f;
  #pragma unroll
  for (int j = 0; j < 3; j++) {
    const float dx = xq[j].x-mean, dy = xq[j].y-mean, dz = xq[j].z-mean, dw = xq[j].w-mean;
    ss += dx*dx + dy*dy + dz*dz + dw*dw;
  }
  #pragma unroll
  for (int m = 1; m < 64; m <<= 1) ss += __shfl_xor(ss, m, 64);
  const float rinv = rsqrtf(ss * (1.0f / 768.0f) + 1e-5f);
  const size_t ob = (size_t)row * D_;
  #pragma unroll
  for (int j = 0; j < 3; j++) {
    const int c = (j*64 + l) * 4;
    const float4 wv = *(const float4*)(w + c);
    const float4 bv = *(const float4*)(b + c);
    ushort4 ov;
    ov.x = f2bf((xq[j].x - mean) * rinv * wv.x + bv.x);
    ov.y = f2bf((xq[j].y - mean) * rinv * wv.y + bv.y);
    ov.z = f2bf((xq[j].z - mean) * rinv * wv.z + bv.z);
    ov.w = f2bf((xq[j].w - mean) * rinv * wv.w + bv.w);
    *(ushort4*)(out + ob + c) = ov;
  }
}

// Final LN over cls rows -> yb[128][768] bf16 (rows >= 64 zeroed)
__global__ void lncls_k(const float* __restrict__ z, const float* __restrict__ w,
                        const float* __restrict__ b, u16* __restrict__ out)
{
  const int row = blockIdx.x * 4 + (threadIdx.x >> 6);   // 0..127
  const int l = threadIdx.x & 63;
  const size_t ob = (size_t)row * D_;
  if (row >= B_) {
    #pragma unroll
    for (int j = 0; j < 12; j++) out[ob + j*64 + l] = 0;
    return;
  }
  const float* zr = z + (size_t)row * NT_ * D_;
  float xv[12];
  float s = 0.f;
  #pragma unroll
  for (int j = 0; j < 12; j++) { xv[j] = zr[j*64 + l]; s += xv[j]; }
  #pragma unroll
  for (int m = 1; m < 64; m <<= 1) s += __shfl_xor(s, m, 64);
  const float mean = s * (1.0f / 768.0f);
  float ss = 0.f;
  #pragma unroll
  for (int j = 0; j < 12; j++) { const float d = xv[j] - mean; ss += d * d; }
  #pragma unroll
  for (int m = 1; m < 64; m <<= 1) ss += __shfl_xor(ss, m, 64);
  const float rinv = rsqrtf(ss * (1.0f / 768.0f) + 1e-5f);
  #pragma unroll
  for (int j = 0; j < 12; j++) {
    const int cidx = j*64 + l;
    out[ob + cidx] = f2bf((xv[j] - mean) * rinv * w[cidx] + b[cidx]);
  }
}

// ---------------------------------------------------------------------------
// MFMA per-token head-axis attention (round-3 proven).
// ---------------------------------------------------------------------------
__global__ __launch_bounds__(256) void attn_k(const u16* __restrict__ qkv,
                                              u16* __restrict__ o)
{
  const int tok = (blockIdx.x * 256 + threadIdx.x) >> 6;
  const int l  = threadIdx.x & 63;
  const int g  = l >> 4, li = l & 15;
  const size_t rb = (size_t)tok * (3 * D_);

  f32x4 s = {0.f, 0.f, 0.f, 0.f};
  #pragma unroll
  for (int kt = 0; kt < 2; kt++) {
    const bf16x8 ka = *(const bf16x8*)(qkv + rb + D_ + li*64 + g*8 + kt*32);
    const bf16x8 qb = *(const bf16x8*)(qkv + rb +      li*64 + g*8 + kt*32);
    s = __builtin_amdgcn_mfma_f32_16x16x32_bf16(ka, qb, s, 0, 0, 0);
  }

  float sv[4];
  #pragma unroll
  for (int r2 = 0; r2 < 4; r2++) sv[r2] = s[r2] * 0.125f;
  float mx = (g < 3) ? fmaxf(fmaxf(sv[0], sv[1]), fmaxf(sv[2], sv[3])) : -1e30f;
  mx = fmaxf(mx, __shfl_xor(mx, 16, 64));
  mx = fmaxf(mx, __shfl_xor(mx, 32, 64));
  float p[4], den = 0.f;
  #pragma unroll
  for (int r2 = 0; r2 < 4; r2++) {
    p[r2] = (g < 3) ? __expf(sv[r2] - mx) : 0.f;
    den += p[r2];
  }
  den += __shfl_xor(den, 16, 64);
  den += __shfl_xor(den, 32, 64);
  const float rden = 1.0f / den;
  #pragma unroll
  for (int r2 = 0; r2 < 4; r2++) p[r2] *= rden;

  const u32 pk01 = ((u32)f2bf(p[1]) << 16) | f2bf(p[0]);
  const u32 pk23 = ((u32)f2bf(p[3]) << 16) | f2bf(p[2]);

  const int srcA = (li + (g << 5)) & 63;
  const int srcB = (srcA + 16) & 63;
  u32 b0 = (u32)__shfl((int)pk01, srcA, 64);
  u32 b1 = (u32)__shfl((int)pk23, srcA, 64);
  u32 b2 = (u32)__shfl((int)pk01, srcB, 64);
  u32 b3 = (u32)__shfl((int)pk23, srcB, 64);
  if (g >= 2) { b0 = 0; b1 = 0; b2 = 0; b3 = 0; }
  union { u32 u[4]; bf16x8 v; } pb;
  pb.u[0] = b0; pb.u[1] = b1; pb.u[2] = b2; pb.u[3] = b3;

  const size_t ob = (size_t)tok * D_;
  #pragma unroll
  for (int t = 0; t < 4; t++) {
    union { u16 a[8]; bf16x8 v; } va;
    #pragma unroll
    for (int jp = 0; jp < 8; jp++) {
      const int j = g * 8 + jp;
      va.a[jp] = (j < 12) ? qkv[rb + 2*D_ + j*64 + t*16 + li] : (u16)0;
    }
    f32x4 oac = {0.f, 0.f, 0.f, 0.f};
    oac = __builtin_amdgcn_mfma_f32_16x16x32_bf16(va.v, pb.v, oac, 0, 0, 0);
    if (li < 12) {
      ushort4 ov;
      ov.x = f2bf(oac[0]); ov.y = f2bf(oac[1]);
      ov.z = f2bf(oac[2]); ov.w = f2bf(oac[3]);
      *(ushort4*)(o + ob + li*64 + t*16 + g*4) = ov;
    }
  }
}

// ---------------------------------------------------------------------------
extern "C" void kernel_launch(void* const* d_in, const int* in_sizes, int n_in,
                              void* d_out, int out_size, void* d_ws, size_t ws_size,
                              hipStream_t stream)
{
  const float* x    = (const float*)d_in[0];
  const float* ce   = (const float*)d_in[1];
  const float* pe   = (const float*)d_in[2];
  const float* pw   = (const float*)d_in[3];
  const float* pb   = (const float*)d_in[4];
  const float* qkvw = (const float*)d_in[5];
  const float* qkvb = (const float*)d_in[6];
  const float* topw = (const float*)d_in[7];
  const float* topb = (const float*)d_in[8];
  const float* l1w  = (const float*)d_in[9];
  const float* l1b  = (const float*)d_in[10];
  const float* l2w  = (const float*)d_in[11];
  const float* l2b  = (const float*)d_in[12];
  const float* w1   = (const float*)d_in[13];
  const float* b1   = (const float*)d_in[14];
  const float* w2   = (const float*)d_in[15];
  const float* b2   = (const float*)d_in[16];
  const float* l3w  = (const float*)d_in[17];
  const float* l3b  = (const float*)d_in[18];
  const float* hw1  = (const float*)d_in[19];
  const float* hb1  = (const float*)d_in[20];
  const float* hw2  = (const float*)d_in[21];
  const float* hb2  = (const float*)d_in[22];

  char* ws = (char*)d_ws;
  constexpr size_t SZ_Z  = (size_t)MPAD2 * D_ * 4;
  constexpr size_t SZ_HB = (size_t)MPAD2 * D_ * 2;
  constexpr size_t SZ_QM = (size_t)MPAD2 * DM_ * 2;
  constexpr size_t SZ_WB = (size_t)DM_ * 1024 * 2;
  constexpr size_t SZ_YB = (size_t)128 * D_ * 2;
  float* z  = (float*)ws;
  u16*   hb = (u16*)(ws + SZ_Z);
  u16*   qm = (u16*)(ws + SZ_Z + SZ_HB);
  u16*   wb = (u16*)(ws + SZ_Z + SZ_HB + SZ_QM);
  u16*   yb = (u16*)(ws + SZ_Z + SZ_HB + SZ_QM + SZ_WB);
  u16*   t1 = (u16*)(ws + SZ_Z + SZ_HB + SZ_QM + SZ_WB + SZ_YB);

  const dim3 blk(256);
  const dim3 blk5(512);
  const dim3 wblk(32, 8);
  const int MT1 = MPAD2 / 128;  // 290
  const int MT2 = MPAD2 / 256;  // 145

  // Patch embedding
  patchify_k<<<B_ * NP_, blk, 0, stream>>>(x, hb);
  wconv_k<<<dim3(D_/32, D_/32), wblk, 0, stream>>>(pw, wb, D_, D_);
  gemm256_k<4><<<3*MT2, blk5, 0, stream>>>(hb, wb, pb, nullptr, z, D_, D_, 3);
  posecls_k<<<MREAL, blk, 0, stream>>>(z, ce, pe);

  for (int i = 0; i < NL_; i++) {
    ln_k<<<MPAD2/4, blk, 0, stream>>>(z, l1w + i*D_, l1b + i*D_, hb);
    wconv_k<<<dim3(3*D_/32, D_/32), wblk, 0, stream>>>(qkvw + (size_t)i*D_*3*D_, wb, D_, 3*D_);
    gemmR_k<0><<<18*MT1, blk, 0, stream>>>(hb, wb, qkvb + i*3*D_, qm, D_, 3*D_, 18);
    attn_k<<<MREAL/4, blk, 0, stream>>>(qm, hb);
    wconv_k<<<dim3(D_/32, D_/32), wblk, 0, stream>>>(topw + (size_t)i*D_*D_, wb, D_, D_);
    gemm256_k<1><<<3*MT2, blk5, 0, stream>>>(hb, wb, topb + i*D_, z, z, D_, D_, 3);
    ln_k<<<MPAD2/4, blk, 0, stream>>>(z, l2w + i*D_, l2b + i*D_, hb);
    wconv_k<<<dim3(DM_/32, D_/32), wblk, 0, stream>>>(w1 + (size_t)i*D_*DM_, wb, D_, DM_);
    gemmR_k<2><<<24*MT1, blk, 0, stream>>>(hb, wb, b1 + i*DM_, qm, D_, DM_, 24);
    wconv_k<<<dim3(D_/32, DM_/32), wblk, 0, stream>>>(w2 + (size_t)i*DM_*D_, wb, DM_, D_);
    gemm256_k<3><<<3*MT2, blk5, 0, stream>>>(qm, wb, b2 + i*D_, z, z, DM_, D_, 3);
  }

  // Head: LN(cls) -> MLP with gelu after both linears (small M -> old kernel)
  lncls_k<<<32, blk, 0, stream>>>(z, l3w, l3b, yb);
  wconv_k<<<dim3(DM_/32, D_/32), wblk, 0, stream>>>(hw1, wb, D_, DM_);
  gemm_k<2><<<24, blk, 0, stream>>>(yb, wb, hb1, nullptr, t1, D_, DM_, 24, 0, 0);
  wconv_k<<<dim3(1024/32, DM_/32), wblk, 0, stream>>>(hw2, wb, DM_, NC_);
  gemm_k<5><<<8, blk, 0, stream>>>(t1, wb, hb2, nullptr, (float*)d_out, DM_, 1024, 8, B_, NC_);
}